// Round 3
// baseline (363.981 us; speedup 1.0000x reference)
//
#include <hip/hip_runtime.h>
#include <hip/hip_bf16.h>

#define N_NODES 50000
#define E_EDGES 800000
#define IN_DIM  128
#define OUT_DIM 64

// ws budget note: round-1 proved ws_size >= 13.2 MB; round-2's 16.8 MB layout
// corrupted adjacent memory (post-timing divergence). This layout uses 7.2 MB.

__device__ __forceinline__ float bcast_lane(float v, int lane) {
    return __uint_as_float(__builtin_amdgcn_readlane(__float_as_uint(v), lane));
}

// ---------------------------------------------------------------------------
// K0: u1 = W_fc^T @ W_att[0:64], u2 = W_fc^T @ W_att[64:128],
//     c12 = {b_fc . w1, b_fc . w2}.  One block, 128 threads. Trivial cost.
// ---------------------------------------------------------------------------
__global__ void gat_prep(const float* __restrict__ Wfc,
                         const float* __restrict__ Watt,
                         const float* __restrict__ bfc,
                         float* __restrict__ u1, float* __restrict__ u2,
                         float* __restrict__ c12)
{
    const int t = threadIdx.x;  // 0..127
    float a = 0.0f, b = 0.0f;
    for (int o = 0; o < OUT_DIM; ++o) {
        const float w = Wfc[o * IN_DIM + t];
        a += Watt[o] * w;
        b += Watt[OUT_DIM + o] * w;
    }
    u1[t] = a;
    u2[t] = b;
    if (t == 0) {
        float c = 0.0f;
        for (int o = 0; o < OUT_DIM; ++o) c += bfc[o] * Watt[o];
        c12[0] = c;
    }
    if (t == 1) {
        float c = 0.0f;
        for (int o = 0; o < OUT_DIM; ++o) c += bfc[o] * Watt[OUT_DIM + o];
        c12[1] = c;
    }
}

// ---------------------------------------------------------------------------
// K1: s1[n] = h[n].u1 + c1,  s2[n] = h[n].u2 + c2.  Wave per node.
// One streaming pass over h (25.6 MB).
// ---------------------------------------------------------------------------
__global__ __launch_bounds__(256) void gat_scal(
    const float* __restrict__ h,
    const float* __restrict__ u1, const float* __restrict__ u2,
    const float* __restrict__ c12,
    float* __restrict__ s1, float* __restrict__ s2)
{
    const int lane = threadIdx.x & 63;
    const int n    = (blockIdx.x * 256 + threadIdx.x) >> 6;
    if (n >= N_NODES) return;

    const float2 hv = *(const float2*)(h + (size_t)n * IN_DIM + 2 * lane);
    const float2 a1 = *(const float2*)(u1 + 2 * lane);
    const float2 a2 = *(const float2*)(u2 + 2 * lane);
    float p1 = hv.x * a1.x + hv.y * a1.y;
    float p2 = hv.x * a2.x + hv.y * a2.y;
    #pragma unroll
    for (int off = 32; off > 0; off >>= 1) {
        p1 += __shfl_xor(p1, off, 64);
        p2 += __shfl_xor(p2, off, 64);
    }
    if (lane == 0) { s1[n] = p1 + c12[0]; s2[n] = p2 + c12[1]; }
}

// ---------------------------------------------------------------------------
// K2: histogram of dst into cnt[] (aliases cursor, pre-zeroed by memset)
// ---------------------------------------------------------------------------
__global__ __launch_bounds__(256) void gat_hist(
    const int* __restrict__ adj, int* __restrict__ cnt)
{
    int e = blockIdx.x * 256 + threadIdx.x;
    if (e < E_EDGES) atomicAdd(&cnt[adj[E_EDGES + e]], 1);
}

// ---------------------------------------------------------------------------
// K3a/b/c: exclusive scan of cnt[50000] -> off[], cursor[i] = off[i]
// ---------------------------------------------------------------------------
__global__ __launch_bounds__(256) void scan_a(
    const int* __restrict__ cnt, int* __restrict__ off, int* __restrict__ bsum)
{
    __shared__ int s[256];
    const int t = threadIdx.x;
    const int i = blockIdx.x * 256 + t;
    int v = (i < N_NODES) ? cnt[i] : 0;
    s[t] = v;
    __syncthreads();
    #pragma unroll
    for (int o = 1; o < 256; o <<= 1) {
        int add = (t >= o) ? s[t - o] : 0;
        __syncthreads();
        s[t] += add;
        __syncthreads();
    }
    if (i < N_NODES) off[i] = s[t] - v;
    if (t == 255) bsum[blockIdx.x] = s[255];
}

__global__ __launch_bounds__(256) void scan_b(int* __restrict__ bsum,
                                              int* __restrict__ off)
{
    __shared__ int s[256];
    const int t = threadIdx.x;
    const int nblk = (N_NODES + 255) / 256;
    int v = (t < nblk) ? bsum[t] : 0;
    s[t] = v;
    __syncthreads();
    #pragma unroll
    for (int o = 1; o < 256; o <<= 1) {
        int add = (t >= o) ? s[t - o] : 0;
        __syncthreads();
        s[t] += add;
        __syncthreads();
    }
    if (t < nblk) bsum[t] = s[t] - v;
    if (t == 0) off[N_NODES] = E_EDGES;
}

__global__ __launch_bounds__(256) void scan_c(
    int* __restrict__ off, int* __restrict__ cursor,
    const int* __restrict__ bsum)
{
    const int i = blockIdx.x * 256 + threadIdx.x;
    if (i < N_NODES) {
        int v = off[i] + bsum[blockIdx.x];
        off[i] = v;
        cursor[i] = v;
    }
}

// ---------------------------------------------------------------------------
// K4: scatter (src, att) into dst-sorted order. att precomputed here so the
// gather inner loop has no dependent scalar-load chain.
// ---------------------------------------------------------------------------
__global__ __launch_bounds__(256) void gat_scatter(
    const int* __restrict__ adj, const float* __restrict__ s1,
    const float* __restrict__ s2, const float* __restrict__ batt,
    int* __restrict__ cursor, int* __restrict__ srcs,
    float* __restrict__ atts)
{
    int e = blockIdx.x * 256 + threadIdx.x;
    if (e < E_EDGES) {
        const int src = adj[e];
        const int dst = adj[E_EDGES + e];
        const int pos = atomicAdd(&cursor[dst], 1);
        const float logit = s1[src] + s2[dst] + batt[0];
        const float att = (logit > 0.0f) ? logit : 0.01f * logit;
        srcs[pos] = src;
        atts[pos] = att;
    }
}

// ---------------------------------------------------------------------------
// K5: gather in h-space + fused output transform.
//   g[n] = sum_e att_e * h[src_e]   (128-dim, float2/lane, registers)
//   out[n] = W_fc @ g[n] + (sum_e att_e) * b_fc
// Wave handles 4 consecutive nodes -> W^T LDS reads amortized 4x.
// wt padded to 65 -> 2-way bank aliasing only (free). g broadcast via
// readlane (no LDS round-trip). Out row written exactly once, no atomics.
// ---------------------------------------------------------------------------
__global__ __launch_bounds__(256) void gat_gather(
    const int* __restrict__ off, const int* __restrict__ srcs,
    const float* __restrict__ atts, const float* __restrict__ h,
    const float* __restrict__ Wfc, const float* __restrict__ bfc,
    float* __restrict__ out)
{
    __shared__ float wt[IN_DIM][OUT_DIM + 1];   // transposed W, 33.3 KB
    for (int i = threadIdx.x; i < OUT_DIM * IN_DIM; i += 256) {
        int o = i >> 7;           // row in Wfc (/128)
        int k = i & 127;
        wt[k][o] = Wfc[i];
    }
    __syncthreads();

    const int lane = threadIdx.x & 63;
    const int wave = threadIdx.x >> 6;
    const int n0   = (blockIdx.x * 4 + wave) * 4;   // 4 nodes per wave
    if (n0 >= N_NODES) return;

    const float bl = bfc[lane];

    float2 g[4];
    float  asum[4];
    #pragma unroll
    for (int r = 0; r < 4; ++r) {
        g[r] = make_float2(0.0f, 0.0f);
        asum[r] = 0.0f;
        const int n  = n0 + r;
        const int jb = off[n];
        const int je = off[n + 1];
        for (int j = jb; j < je; ++j) {
            const int   src = srcs[j];
            const float att = atts[j];
            const float2 hv = *(const float2*)(h + (size_t)src * IN_DIM + 2 * lane);
            g[r].x += att * hv.x;
            g[r].y += att * hv.y;
            asum[r] += att;
        }
    }

    float acc[4];
    #pragma unroll
    for (int r = 0; r < 4; ++r) acc[r] = asum[r] * bl;

    #pragma unroll 8
    for (int kk = 0; kk < 64; ++kk) {
        const float w0 = wt[2 * kk][lane];
        const float w1 = wt[2 * kk + 1][lane];
        #pragma unroll
        for (int r = 0; r < 4; ++r) {
            const float gx = bcast_lane(g[r].x, kk);
            const float gy = bcast_lane(g[r].y, kk);
            acc[r] += gx * w0 + gy * w1;
        }
    }

    #pragma unroll
    for (int r = 0; r < 4; ++r)
        out[(size_t)(n0 + r) * OUT_DIM + lane] = acc[r];
}

extern "C" void kernel_launch(void* const* d_in, const int* in_sizes, int n_in,
                              void* d_out, int out_size, void* d_ws, size_t ws_size,
                              hipStream_t stream)
{
    const int*   adj  = (const int*)  d_in[0];   // (2, E)
    const float* h    = (const float*)d_in[1];   // (N, 128)
    const float* Wfc  = (const float*)d_in[2];   // (64, 128)
    const float* bfc  = (const float*)d_in[3];   // (64,)
    const float* Watt = (const float*)d_in[4];   // (1, 128)
    const float* batt = (const float*)d_in[5];   // (1,)
    float* out = (float*)d_out;                  // (N, 64)

    // ws layout (4B units), total ~7.2 MB:
    // u1[128] | u2[128] | c12[2] | s1[N] | s2[N] | off[N+1] | cursor[N] |
    // bsum[256] | srcs[E] | atts[E]
    float* u1     = (float*)d_ws;
    float* u2     = u1 + IN_DIM;
    float* c12    = u2 + IN_DIM;
    float* s1     = c12 + 2;
    float* s2     = s1 + N_NODES;
    int*   off    = (int*)(s2 + N_NODES);
    int*   cursor = off + (N_NODES + 1);
    int*   bsum   = cursor + N_NODES;
    int*   srcs   = bsum + 256;
    float* atts   = (float*)(srcs + E_EDGES);

    const int nblk_nodes = (N_NODES + 255) / 256;   // 196
    const int nblk_edges = (E_EDGES + 255) / 256;   // 3125

    hipMemsetAsync(cursor, 0, N_NODES * sizeof(int), stream);

    gat_prep<<<1, 128, 0, stream>>>(Wfc, Watt, bfc, u1, u2, c12);
    gat_scal<<<(N_NODES * 64 + 255) / 256, 256, 0, stream>>>(h, u1, u2, c12, s1, s2);
    gat_hist<<<nblk_edges, 256, 0, stream>>>(adj, cursor);
    scan_a<<<nblk_nodes, 256, 0, stream>>>(cursor, off, bsum);
    scan_b<<<1, 256, 0, stream>>>(bsum, off);
    scan_c<<<nblk_nodes, 256, 0, stream>>>(off, cursor, bsum);
    gat_scatter<<<nblk_edges, 256, 0, stream>>>(adj, s1, s2, batt, cursor, srcs, atts);
    // 4 nodes/wave, 4 waves/block -> 16 nodes/block
    gat_gather<<<(N_NODES + 15) / 16, 256, 0, stream>>>(off, srcs, atts, h, Wfc, bfc, out);
}

// Round 4
// 223.402 us; speedup vs baseline: 1.6293x; 1.6293x over previous
//
#include <hip/hip_runtime.h>
#include <hip/hip_bf16.h>

#define N_NODES 50000
#define E_EDGES 800000
#define IN_DIM  128
#define OUT_DIM 64

static_assert(N_NODES < 65536, "src node ids packed as ushort");

// ws budget note: round-1 proved ws_size >= 13.2 MB OK; round-2's 16.8 MB
// corrupted adjacent memory. This layout uses 11.8 MB.

__device__ __forceinline__ unsigned short f32_to_bf16_rne(float f) {
    unsigned u = __float_as_uint(f);
    return (unsigned short)((u + 0x7FFFu + ((u >> 16) & 1u)) >> 16);
}
__device__ __forceinline__ float bf16_to_f32(unsigned short s) {
    return __uint_as_float(((unsigned)s) << 16);
}

// ---------------------------------------------------------------------------
// K1: z16 = bf16(h @ W_fc^T + b_fc), s1[n]=z.w1, s2[n]=z.w2, fused dst-hist.
// Wave per 4-node group; lane = out dim. W^T in LDS (65-pad). h rows staged
// wave-privately via coalesced float4 + LDS (no barrier needed: same-wave
// RAW, compiler inserts lgkmcnt). Validated structure (round-2 first check).
// ---------------------------------------------------------------------------
__global__ __launch_bounds__(256) void gat_fc(
    const float* __restrict__ h,
    const float* __restrict__ Wfc,
    const float* __restrict__ bfc,
    const float* __restrict__ Watt,
    const int*   __restrict__ adj,
    unsigned short* __restrict__ z16,
    float* __restrict__ s1,
    float* __restrict__ s2,
    int*   __restrict__ cnt)
{
    __shared__ float wt[IN_DIM][OUT_DIM + 1];   // 33.3 KB
    __shared__ float hbuf[4][4 * IN_DIM];       // 8 KB

    for (int i = threadIdx.x; i < OUT_DIM * IN_DIM; i += 256) {
        int o = i >> 7;            // /128
        int k = i & 127;
        wt[k][o] = Wfc[i];
    }
    __syncthreads();

    const int lane  = threadIdx.x & 63;
    const int wave  = threadIdx.x >> 6;
    const int group = blockIdx.x * 4 + wave;
    const int ngrp  = gridDim.x * 4;

    const float bias = bfc[lane];
    const float w1l  = Watt[lane];
    const float w2l  = Watt[OUT_DIM + lane];

    for (int n0 = group * 4; n0 < N_NODES; n0 += ngrp * 4) {   // N%4==0
        const float* hp = h + (size_t)n0 * IN_DIM + lane * 8;
        float4 a = *(const float4*)(hp);
        float4 b = *(const float4*)(hp + 4);
        *(float4*)&hbuf[wave][lane * 8]     = a;
        *(float4*)&hbuf[wave][lane * 8 + 4] = b;

        float acc0 = bias, acc1 = bias, acc2 = bias, acc3 = bias;
        #pragma unroll
        for (int k = 0; k < IN_DIM; k += 4) {
            float w0 = wt[k + 0][lane];
            float w1 = wt[k + 1][lane];
            float w2 = wt[k + 2][lane];
            float w3 = wt[k + 3][lane];
            float4 h0 = *(const float4*)&hbuf[wave][0 * IN_DIM + k];
            float4 h1 = *(const float4*)&hbuf[wave][1 * IN_DIM + k];
            float4 h2 = *(const float4*)&hbuf[wave][2 * IN_DIM + k];
            float4 h3 = *(const float4*)&hbuf[wave][3 * IN_DIM + k];
            acc0 += h0.x * w0 + h0.y * w1 + h0.z * w2 + h0.w * w3;
            acc1 += h1.x * w0 + h1.y * w1 + h1.z * w2 + h1.w * w3;
            acc2 += h2.x * w0 + h2.y * w1 + h2.z * w2 + h2.w * w3;
            acc3 += h3.x * w0 + h3.y * w1 + h3.z * w2 + h3.w * w3;
        }

        unsigned short* zp = z16 + (size_t)n0 * OUT_DIM + lane;
        zp[0 * OUT_DIM] = f32_to_bf16_rne(acc0);
        zp[1 * OUT_DIM] = f32_to_bf16_rne(acc1);
        zp[2 * OUT_DIM] = f32_to_bf16_rne(acc2);
        zp[3 * OUT_DIM] = f32_to_bf16_rne(acc3);

        float accs[4] = {acc0, acc1, acc2, acc3};
        #pragma unroll
        for (int r = 0; r < 4; ++r) {
            float p1 = accs[r] * w1l;
            float p2 = accs[r] * w2l;
            #pragma unroll
            for (int off = 32; off > 0; off >>= 1) {
                p1 += __shfl_xor(p1, off, 64);
                p2 += __shfl_xor(p2, off, 64);
            }
            if (lane == 0) { s1[n0 + r] = p1; s2[n0 + r] = p2; }
        }
    }

    // fused dst histogram (independent of the z work above)
    const int tid  = blockIdx.x * 256 + threadIdx.x;
    const int nthr = gridDim.x * 256;
    for (int e = tid; e < E_EDGES; e += nthr)
        atomicAdd(&cnt[adj[E_EDGES + e]], 1);
}

// ---------------------------------------------------------------------------
// K2a/b/c: exclusive scan of cursor[50000] in place (counts -> start offsets)
// ---------------------------------------------------------------------------
__global__ __launch_bounds__(256) void scan_a(
    int* __restrict__ cur, int* __restrict__ bsum)
{
    __shared__ int s[256];
    const int t = threadIdx.x;
    const int i = blockIdx.x * 256 + t;
    int v = (i < N_NODES) ? cur[i] : 0;
    s[t] = v;
    __syncthreads();
    #pragma unroll
    for (int o = 1; o < 256; o <<= 1) {
        int add = (t >= o) ? s[t - o] : 0;
        __syncthreads();
        s[t] += add;
        __syncthreads();
    }
    if (i < N_NODES) cur[i] = s[t] - v;      // exclusive
    if (t == 255) bsum[blockIdx.x] = s[255];
}

__global__ __launch_bounds__(256) void scan_b(int* __restrict__ bsum)
{
    __shared__ int s[256];
    const int t = threadIdx.x;
    const int nblk = (N_NODES + 255) / 256;
    int v = (t < nblk) ? bsum[t] : 0;
    s[t] = v;
    __syncthreads();
    #pragma unroll
    for (int o = 1; o < 256; o <<= 1) {
        int add = (t >= o) ? s[t - o] : 0;
        __syncthreads();
        s[t] += add;
        __syncthreads();
    }
    if (t < nblk) bsum[t] = s[t] - v;        // exclusive block offsets
}

__global__ __launch_bounds__(256) void scan_c(
    int* __restrict__ cur, const int* __restrict__ bsum)
{
    const int i = blockIdx.x * 256 + threadIdx.x;
    if (i < N_NODES) cur[i] += bsum[blockIdx.x];
}

// ---------------------------------------------------------------------------
// K3: scatter (src:ushort, att:f32) into dst-sorted order.
// After this kernel cursor[n] == segment END of node n (== start of n+1).
// ---------------------------------------------------------------------------
__global__ __launch_bounds__(256) void gat_scatter(
    const int* __restrict__ adj, const float* __restrict__ s1,
    const float* __restrict__ s2, const float* __restrict__ batt,
    int* __restrict__ cursor, unsigned short* __restrict__ srcs,
    float* __restrict__ atts)
{
    const int e = blockIdx.x * 256 + threadIdx.x;
    if (e >= E_EDGES) return;
    const int src = adj[e];
    const int dst = adj[E_EDGES + e];
    const float logit = s1[src] + s2[dst] + batt[0];
    const float att   = (logit > 0.0f) ? logit : 0.01f * logit;
    const int pos = atomicAdd(&cursor[dst], 1);
    srcs[pos] = (unsigned short)src;
    atts[pos] = att;
}

// ---------------------------------------------------------------------------
// K4: gather in z-space. Wave per node; lane = feature. Per edge: one
// 2B/lane load of the bf16 z row (128 B/wave, z16 = 6.4 MB -> L2/L3-hot).
// Unroll-by-4 to overlap the src->z dependent-load chains. No epilogue
// matvec, no LDS, out row written exactly once.
// ---------------------------------------------------------------------------
__global__ __launch_bounds__(256) void gat_gather(
    const int* __restrict__ cursor, const unsigned short* __restrict__ srcs,
    const float* __restrict__ atts, const unsigned short* __restrict__ z16,
    float* __restrict__ out)
{
    const int lane = threadIdx.x & 63;
    const int n    = (blockIdx.x * 256 + threadIdx.x) >> 6;
    if (n >= N_NODES) return;

    const int jb = (n == 0) ? 0 : cursor[n - 1];
    const int je = cursor[n];

    float acc = 0.0f;
    int j = jb;
    for (; j + 4 <= je; j += 4) {
        const int s0 = srcs[j + 0];
        const int s1_ = srcs[j + 1];
        const int s2_ = srcs[j + 2];
        const int s3 = srcs[j + 3];
        const float a0 = atts[j + 0];
        const float a1 = atts[j + 1];
        const float a2 = atts[j + 2];
        const float a3 = atts[j + 3];
        const float z0 = bf16_to_f32(z16[(size_t)s0 * OUT_DIM + lane]);
        const float z1 = bf16_to_f32(z16[(size_t)s1_ * OUT_DIM + lane]);
        const float z2 = bf16_to_f32(z16[(size_t)s2_ * OUT_DIM + lane]);
        const float z3 = bf16_to_f32(z16[(size_t)s3 * OUT_DIM + lane]);
        acc += a0 * z0 + a1 * z1 + a2 * z2 + a3 * z3;
    }
    for (; j < je; ++j)
        acc += atts[j] * bf16_to_f32(z16[(size_t)srcs[j] * OUT_DIM + lane]);

    out[(size_t)n * OUT_DIM + lane] = acc;
}

extern "C" void kernel_launch(void* const* d_in, const int* in_sizes, int n_in,
                              void* d_out, int out_size, void* d_ws, size_t ws_size,
                              hipStream_t stream)
{
    const int*   adj  = (const int*)  d_in[0];   // (2, E)
    const float* h    = (const float*)d_in[1];   // (N, 128)
    const float* Wfc  = (const float*)d_in[2];   // (64, 128)
    const float* bfc  = (const float*)d_in[3];   // (64,)
    const float* Watt = (const float*)d_in[4];   // (1, 128)
    const float* batt = (const float*)d_in[5];   // (1,)
    float* out = (float*)d_out;                  // (N, 64)

    // ws layout (total 11.8 MB):
    // z16[N*64] u16 (6.4M) | s1[N] f32 | s2[N] f32 | cursor[N] i32 |
    // bsum[256] i32 | srcs[E] u16 (1.6M) | atts[E] f32 (3.2M)
    unsigned short* z16 = (unsigned short*)d_ws;
    float* s1     = (float*)(z16 + (size_t)N_NODES * OUT_DIM);
    float* s2     = s1 + N_NODES;
    int*   cursor = (int*)(s2 + N_NODES);
    int*   bsum   = cursor + N_NODES;
    unsigned short* srcs = (unsigned short*)(bsum + 256);
    float* atts   = (float*)(srcs + E_EDGES);   // E even -> 4B aligned

    const int nblk_nodes = (N_NODES + 255) / 256;   // 196
    const int nblk_edges = (E_EDGES + 255) / 256;   // 3125

    hipMemsetAsync(cursor, 0, N_NODES * sizeof(int), stream);

    gat_fc<<<1024, 256, 0, stream>>>(h, Wfc, bfc, Watt, adj, z16, s1, s2, cursor);
    scan_a<<<nblk_nodes, 256, 0, stream>>>(cursor, bsum);
    scan_b<<<1, 256, 0, stream>>>(bsum);
    scan_c<<<nblk_nodes, 256, 0, stream>>>(cursor, bsum);
    gat_scatter<<<nblk_edges, 256, 0, stream>>>(adj, s1, s2, batt, cursor, srcs, atts);
    gat_gather<<<nblk_nodes * 64, 256, 0, stream>>>(cursor, srcs, atts, z16, out);
}

// Round 7
// 205.966 us; speedup vs baseline: 1.7672x; 1.0847x over previous
//
#include <hip/hip_runtime.h>
#include <hip/hip_bf16.h>

#define N_NODES 50000
#define E_EDGES 800000
#define IN_DIM  128
#define OUT_DIM 64
#define MTILES  (N_NODES / 16)   // 3125, exact

static_assert(N_NODES % 16 == 0, "16-row MFMA tiles");
static_assert(N_NODES < 65536, "src node ids packed as ushort");

// ws budget: round-1 proved >=13.2 MB OK; round-2's 16.8 MB corrupted memory.
// This layout: 8.6 MB.

typedef __attribute__((ext_vector_type(8))) short bf16x8;
typedef __attribute__((ext_vector_type(4))) float f32x4;

__device__ __forceinline__ unsigned short f32_to_bf16_rne(float f) {
    unsigned u = __float_as_uint(f);
    return (unsigned short)((u + 0x7FFFu + ((u >> 16) & 1u)) >> 16);
}
__device__ __forceinline__ float bf16_to_f32(unsigned short s) {
    return __uint_as_float(((unsigned)s) << 16);
}

// ---------------------------------------------------------------------------
// K1 (MFMA): z16 = bf16(h @ W^T + b), s1 = z.w1, s2 = z.w2 + b_att, + dst hist.
// One wave per 16-node tile. A-frag: A[m=lane&15][k=quad*8+j] loaded straight
// from h (one 128B line per row per K-step). B-frags (W^T) from block-shared
// bf16 LDS copy, register-resident (64 VGPRs). C/D: col=lane&15,
// row=quad*4+reg (m89-verified). s1/s2 from fp32 accs (quad-local shfl
// reduce). Histogram atomics fire-and-forget (overlap the GEMM).
// ---------------------------------------------------------------------------
__global__ __launch_bounds__(256) void gat_fc(
    const float* __restrict__ h,
    const float* __restrict__ Wfc,
    const float* __restrict__ bfc,
    const float* __restrict__ Watt,
    const float* __restrict__ batt,
    const int*   __restrict__ adj,
    unsigned short* __restrict__ z16,
    float* __restrict__ s1,
    float* __restrict__ s2,
    int*   __restrict__ cnt)
{
    __shared__ short Wlds[OUT_DIM * IN_DIM];   // 16 KB, bf16 W[n][k]
    for (int i = threadIdx.x; i < OUT_DIM * IN_DIM; i += 256)
        Wlds[i] = (short)f32_to_bf16_rne(Wfc[i]);
    __syncthreads();

    const int lane  = threadIdx.x & 63;
    const int c     = lane & 15;          // A row / B col / C col
    const int q     = lane >> 4;          // quad
    const int mtile = blockIdx.x * 4 + (threadIdx.x >> 6);

    if (mtile < MTILES) {
        const int n0 = mtile * 16;

        // B fragments: B[k=t*32+q*8+j][n=f*16+c] = W[f*16+c][t*32+q*8+j]
        bf16x8 B[4][4];
        #pragma unroll
        for (int t = 0; t < 4; ++t)
            #pragma unroll
            for (int f = 0; f < 4; ++f)
                B[t][f] = *(const bf16x8*)&Wlds[(f * 16 + c) * IN_DIM + t * 32 + q * 8];

        f32x4 acc[4] = {{0,0,0,0},{0,0,0,0},{0,0,0,0},{0,0,0,0}};

        const float* arow = h + (size_t)(n0 + c) * IN_DIM + q * 8;
        #pragma unroll
        for (int t = 0; t < 4; ++t) {
            float4 x0 = *(const float4*)(arow + t * 32);
            float4 x1 = *(const float4*)(arow + t * 32 + 4);
            bf16x8 a;
            a[0] = (short)f32_to_bf16_rne(x0.x);
            a[1] = (short)f32_to_bf16_rne(x0.y);
            a[2] = (short)f32_to_bf16_rne(x0.z);
            a[3] = (short)f32_to_bf16_rne(x0.w);
            a[4] = (short)f32_to_bf16_rne(x1.x);
            a[5] = (short)f32_to_bf16_rne(x1.y);
            a[6] = (short)f32_to_bf16_rne(x1.z);
            a[7] = (short)f32_to_bf16_rne(x1.w);
            #pragma unroll
            for (int f = 0; f < 4; ++f)
                acc[f] = __builtin_amdgcn_mfma_f32_16x16x32_bf16(a, B[t][f], acc[f], 0, 0, 0);
        }

        // epilogue: bias, z16 stores, s1/s2 partials
        const float batt0 = batt[0];
        float w1c[4], w2c[4], bv[4];
        #pragma unroll
        for (int f = 0; f < 4; ++f) {
            w1c[f] = Watt[f * 16 + c];
            w2c[f] = Watt[OUT_DIM + f * 16 + c];
            bv[f]  = bfc[f * 16 + c];
        }
        float p1[4] = {0,0,0,0}, p2[4] = {0,0,0,0};
        #pragma unroll
        for (int f = 0; f < 4; ++f)
            #pragma unroll
            for (int r = 0; r < 4; ++r) {
                const float v = acc[f][r] + bv[f];
                z16[(size_t)(n0 + q * 4 + r) * OUT_DIM + f * 16 + c] = f32_to_bf16_rne(v);
                p1[r] += v * w1c[f];
                p2[r] += v * w2c[f];
            }
        #pragma unroll
        for (int r = 0; r < 4; ++r) {
            #pragma unroll
            for (int off = 1; off < 16; off <<= 1) {   // quad-local 16-lane reduce
                p1[r] += __shfl_xor(p1[r], off, 64);
                p2[r] += __shfl_xor(p2[r], off, 64);
            }
            if (c == 0) {
                s1[n0 + q * 4 + r] = p1[r];
                s2[n0 + q * 4 + r] = p2[r] + batt0;   // fold b_att in
            }
        }
    }

    // fused dst histogram (independent; atomics are fire-and-forget)
    const int tid  = blockIdx.x * 256 + threadIdx.x;
    const int nthr = gridDim.x * 256;
    for (int e = tid; e < E_EDGES; e += nthr)
        atomicAdd(&cnt[adj[E_EDGES + e]], 1);
}

// ---------------------------------------------------------------------------
// K2a/b/c: exclusive scan of cursor[50000] in place (counts -> start offsets)
// ---------------------------------------------------------------------------
__global__ __launch_bounds__(256) void scan_a(
    int* __restrict__ cur, int* __restrict__ bsum)
{
    __shared__ int s[256];
    const int t = threadIdx.x;
    const int i = blockIdx.x * 256 + t;
    int v = (i < N_NODES) ? cur[i] : 0;
    s[t] = v;
    __syncthreads();
    #pragma unroll
    for (int o = 1; o < 256; o <<= 1) {
        int add = (t >= o) ? s[t - o] : 0;
        __syncthreads();
        s[t] += add;
        __syncthreads();
    }
    if (i < N_NODES) cur[i] = s[t] - v;
    if (t == 255) bsum[blockIdx.x] = s[255];
}

__global__ __launch_bounds__(256) void scan_b(int* __restrict__ bsum)
{
    __shared__ int s[256];
    const int t = threadIdx.x;
    const int nblk = (N_NODES + 255) / 256;
    int v = (t < nblk) ? bsum[t] : 0;
    s[t] = v;
    __syncthreads();
    #pragma unroll
    for (int o = 1; o < 256; o <<= 1) {
        int add = (t >= o) ? s[t - o] : 0;
        __syncthreads();
        s[t] += add;
        __syncthreads();
    }
    if (t < nblk) bsum[t] = s[t] - v;
}

__global__ __launch_bounds__(256) void scan_c(
    int* __restrict__ cur, const int* __restrict__ bsum)
{
    const int i = blockIdx.x * 256 + threadIdx.x;
    if (i < N_NODES) cur[i] += bsum[blockIdx.x];
}

// ---------------------------------------------------------------------------
// K3: scatter src ids (ushort) into dst-sorted order. Pure int work; att is
// recomputed in the gather (s1/s2 are L2-hot). After this, cursor[n] = END
// of node n's segment.
// ---------------------------------------------------------------------------
__global__ __launch_bounds__(256) void gat_scatter(
    const int* __restrict__ adj,
    int* __restrict__ cursor, unsigned short* __restrict__ srcs)
{
    const int e = blockIdx.x * 256 + threadIdx.x;
    if (e >= E_EDGES) return;
    const int src = adj[e];
    const int dst = adj[E_EDGES + e];
    const int pos = atomicAdd(&cursor[dst], 1);
    srcs[pos] = (unsigned short)src;
}

// ---------------------------------------------------------------------------
// K4: gather, quarter-wave layout. 16 lanes per edge (lane holds 4 features,
// ushort4 = 8B load), 4 edges in flight per iteration -> 4 independent
// src->z dependent chains. att = lrelu(s1[src] + s2'[n]) recomputed (s1 is
// 200 KB, L2-resident; load overlaps the z load). shfl_xor(16,32) reduce,
// quarter 0 stores the row as float4 (256 B coalesced). No atomics.
// ---------------------------------------------------------------------------
__global__ __launch_bounds__(256) void gat_gather(
    const int* __restrict__ cursor, const unsigned short* __restrict__ srcs,
    const float* __restrict__ s1, const float* __restrict__ s2,
    const unsigned short* __restrict__ z16,
    float* __restrict__ out)
{
    const int lane = threadIdx.x & 63;
    const int c    = lane & 15;      // feature group: features 4c..4c+3
    const int q    = lane >> 4;      // edge slot within iteration
    const int n    = blockIdx.x * 4 + (threadIdx.x >> 6);
    if (n >= N_NODES) return;

    const int jb = (n == 0) ? 0 : cursor[n - 1];
    const int je = cursor[n];
    const float s2n = s2[n];         // already includes b_att

    float4 acc = make_float4(0.f, 0.f, 0.f, 0.f);

    int j = jb;
    for (; j + 4 <= je; j += 4) {
        const int src = srcs[j + q];
        float a = s1[src] + s2n;
        a = (a > 0.f) ? a : 0.01f * a;
        const ushort4 zz = *(const ushort4*)&z16[(size_t)src * OUT_DIM + 4 * c];
        acc.x += a * bf16_to_f32(zz.x);
        acc.y += a * bf16_to_f32(zz.y);
        acc.z += a * bf16_to_f32(zz.z);
        acc.w += a * bf16_to_f32(zz.w);
    }
    const int rem = je - j;
    if (q < rem) {
        const int src = srcs[j + q];
        float a = s1[src] + s2n;
        a = (a > 0.f) ? a : 0.01f * a;
        const ushort4 zz = *(const ushort4*)&z16[(size_t)src * OUT_DIM + 4 * c];
        acc.x += a * bf16_to_f32(zz.x);
        acc.y += a * bf16_to_f32(zz.y);
        acc.z += a * bf16_to_f32(zz.z);
        acc.w += a * bf16_to_f32(zz.w);
    }

    // combine the 4 edge slots
    acc.x += __shfl_xor(acc.x, 16, 64);
    acc.y += __shfl_xor(acc.y, 16, 64);
    acc.z += __shfl_xor(acc.z, 16, 64);
    acc.w += __shfl_xor(acc.w, 16, 64);
    acc.x += __shfl_xor(acc.x, 32, 64);
    acc.y += __shfl_xor(acc.y, 32, 64);
    acc.z += __shfl_xor(acc.z, 32, 64);
    acc.w += __shfl_xor(acc.w, 32, 64);

    if (q == 0)
        *(float4*)&out[(size_t)n * OUT_DIM + 4 * c] = acc;
}

extern "C" void kernel_launch(void* const* d_in, const int* in_sizes, int n_in,
                              void* d_out, int out_size, void* d_ws, size_t ws_size,
                              hipStream_t stream)
{
    const int*   adj  = (const int*)  d_in[0];   // (2, E)
    const float* h    = (const float*)d_in[1];   // (N, 128)
    const float* Wfc  = (const float*)d_in[2];   // (64, 128)
    const float* bfc  = (const float*)d_in[3];   // (64,)
    const float* Watt = (const float*)d_in[4];   // (1, 128)
    const float* batt = (const float*)d_in[5];   // (1,)
    float* out = (float*)d_out;                  // (N, 64)

    // ws layout (8.6 MB): z16[N*64] u16 | s1[N] f32 | s2[N] f32 |
    // cursor[N] i32 | bsum[256] i32 | srcs[E] u16
    unsigned short* z16 = (unsigned short*)d_ws;
    float* s1     = (float*)(z16 + (size_t)N_NODES * OUT_DIM);
    float* s2     = s1 + N_NODES;
    int*   cursor = (int*)(s2 + N_NODES);
    int*   bsum   = cursor + N_NODES;
    unsigned short* srcs = (unsigned short*)(bsum + 256);

    const int nblk_nodes = (N_NODES + 255) / 256;   // 196
    const int nblk_edges = (E_EDGES + 255) / 256;   // 3125
    const int nblk_fc    = (MTILES + 3) / 4;        // 782 (4 tiles/block)

    hipMemsetAsync(cursor, 0, N_NODES * sizeof(int), stream);

    gat_fc<<<nblk_fc, 256, 0, stream>>>(h, Wfc, bfc, Watt, batt, adj,
                                        z16, s1, s2, cursor);
    scan_a<<<nblk_nodes, 256, 0, stream>>>(cursor, bsum);
    scan_b<<<1, 256, 0, stream>>>(bsum);
    scan_c<<<nblk_nodes, 256, 0, stream>>>(cursor, bsum);
    gat_scatter<<<nblk_edges, 256, 0, stream>>>(adj, cursor, srcs);
    gat_gather<<<(N_NODES + 3) / 4, 256, 0, stream>>>(cursor, srcs, s1, s2, z16, out);
}

// Round 10
// 177.251 us; speedup vs baseline: 2.0535x; 1.1620x over previous
//
#include <hip/hip_runtime.h>
#include <hip/hip_bf16.h>

#define N_NODES 50000
#define E_EDGES 800000
#define IN_DIM  128
#define OUT_DIM 64
#define MTILES  (N_NODES / 16)   // 3125, exact
#define CAP     48               // per-node bin capacity (mean deg 16, Poisson)
#define OVF_CAP 32768            // overflow list capacity (expected use: 0)

static_assert(N_NODES % 16 == 0, "16-row MFMA tiles");
static_assert(N_NODES < 65536, "node ids packed as ushort");

// ws budget: round-1 proved >=13.2 MB OK; round-2's 16.8 MB corrupted memory.
// This layout: 11.9 MB.

typedef __attribute__((ext_vector_type(8))) short bf16x8;
typedef __attribute__((ext_vector_type(4))) float f32x4;

__device__ __forceinline__ unsigned short f32_to_bf16_rne(float f) {
    unsigned u = __float_as_uint(f);
    return (unsigned short)((u + 0x7FFFu + ((u >> 16) & 1u)) >> 16);
}
__device__ __forceinline__ float bf16_to_f32(unsigned short s) {
    return __uint_as_float(((unsigned)s) << 16);
}

// ---------------------------------------------------------------------------
// K1 (MFMA): z16 = bf16(h @ W^T + b), s1 = z.w1, s2 = z.w2 + b_att.
// Histogram REMOVED (round-7 counters: fused hist's atomic write-through
// was fc's ~40 us floor — WRITE_SIZE 25 MB over z16's 6.4 MB).
// Wlds padded to 136 shorts/row: B-frag ds_read_b128 was 16-way bank
// conflict at stride 128B (1.4M conflict cycles), pad makes it 2-way (free).
// ---------------------------------------------------------------------------
__global__ __launch_bounds__(256) void gat_fc(
    const float* __restrict__ h,
    const float* __restrict__ Wfc,
    const float* __restrict__ bfc,
    const float* __restrict__ Watt,
    const float* __restrict__ batt,
    unsigned short* __restrict__ z16,
    float* __restrict__ s1,
    float* __restrict__ s2)
{
    __shared__ short Wlds[OUT_DIM][IN_DIM + 8];   // 17.4 KB, +16B row pad
    for (int i = threadIdx.x; i < OUT_DIM * IN_DIM; i += 256) {
        const int o = i >> 7;            // /128
        const int k = i & 127;
        Wlds[o][k] = (short)f32_to_bf16_rne(Wfc[i]);
    }
    __syncthreads();

    const int lane  = threadIdx.x & 63;
    const int c     = lane & 15;          // A row / B col / C col
    const int q     = lane >> 4;          // quad
    const int mtile = blockIdx.x * 4 + (threadIdx.x >> 6);
    if (mtile >= MTILES) return;
    const int n0 = mtile * 16;

    // B fragments: B[k=t*32+q*8+j][n=f*16+c] = W[f*16+c][t*32+q*8+j]
    bf16x8 B[4][4];
    #pragma unroll
    for (int t = 0; t < 4; ++t)
        #pragma unroll
        for (int f = 0; f < 4; ++f)
            B[t][f] = *(const bf16x8*)&Wlds[f * 16 + c][t * 32 + q * 8];

    f32x4 acc[4] = {{0,0,0,0},{0,0,0,0},{0,0,0,0},{0,0,0,0}};

    const float* arow = h + (size_t)(n0 + c) * IN_DIM + q * 8;
    #pragma unroll
    for (int t = 0; t < 4; ++t) {
        float4 x0 = *(const float4*)(arow + t * 32);
        float4 x1 = *(const float4*)(arow + t * 32 + 4);
        bf16x8 a;
        a[0] = (short)f32_to_bf16_rne(x0.x);
        a[1] = (short)f32_to_bf16_rne(x0.y);
        a[2] = (short)f32_to_bf16_rne(x0.z);
        a[3] = (short)f32_to_bf16_rne(x0.w);
        a[4] = (short)f32_to_bf16_rne(x1.x);
        a[5] = (short)f32_to_bf16_rne(x1.y);
        a[6] = (short)f32_to_bf16_rne(x1.z);
        a[7] = (short)f32_to_bf16_rne(x1.w);
        #pragma unroll
        for (int f = 0; f < 4; ++f)
            acc[f] = __builtin_amdgcn_mfma_f32_16x16x32_bf16(a, B[t][f], acc[f], 0, 0, 0);
    }

    // epilogue: bias, z16 stores, s1/s2 (quad-local 16-lane reduce)
    const float batt0 = batt[0];
    float w1c[4], w2c[4], bv[4];
    #pragma unroll
    for (int f = 0; f < 4; ++f) {
        w1c[f] = Watt[f * 16 + c];
        w2c[f] = Watt[OUT_DIM + f * 16 + c];
        bv[f]  = bfc[f * 16 + c];
    }
    float p1[4] = {0,0,0,0}, p2[4] = {0,0,0,0};
    #pragma unroll
    for (int f = 0; f < 4; ++f)
        #pragma unroll
        for (int r = 0; r < 4; ++r) {
            const float v = acc[f][r] + bv[f];
            z16[(size_t)(n0 + q * 4 + r) * OUT_DIM + f * 16 + c] = f32_to_bf16_rne(v);
            p1[r] += v * w1c[f];
            p2[r] += v * w2c[f];
        }
    #pragma unroll
    for (int r = 0; r < 4; ++r) {
        #pragma unroll
        for (int off = 1; off < 16; off <<= 1) {
            p1[r] += __shfl_xor(p1[r], off, 64);
            p2[r] += __shfl_xor(p2[r], off, 64);
        }
        if (c == 0) {
            s1[n0 + q * 4 + r] = p1[r];
            s2[n0 + q * 4 + r] = p2[r] + batt0;   // fold b_att in
        }
    }
}

// ---------------------------------------------------------------------------
// K2: capacity-binned scatter — ONE atomic pass (replaces hist+scan+scatter).
// pos = atomicAdd(cnt[dst]) allocates a slot in srcs[dst*CAP .. ]. Overflow
// (P ~ 1e-11 per node at CAP=48, Poisson(16)) goes to a list for K4.
// ---------------------------------------------------------------------------
__global__ __launch_bounds__(256) void gat_scatter(
    const int* __restrict__ adj,
    int* __restrict__ cnt,          // [N] pre-zeroed; cnt+N = ovf_cnt
    unsigned short* __restrict__ srcs,
    int* __restrict__ ovf)
{
    const int e = blockIdx.x * 256 + threadIdx.x;
    if (e >= E_EDGES) return;
    const int src = adj[e];
    const int dst = adj[E_EDGES + e];
    const int pos = atomicAdd(&cnt[dst], 1);
    if (pos < CAP) {
        srcs[(size_t)dst * CAP + pos] = (unsigned short)src;
    } else {
        const int o = atomicAdd(&cnt[N_NODES], 1);   // ovf_cnt
        if (o < OVF_CAP) ovf[o] = (dst << 16) | src;
    }
}

// ---------------------------------------------------------------------------
// K3: gather, quarter-wave layout (validated round 7). 16 lanes/edge,
// ushort4 z loads, 4 edges in flight. att recomputed from L2-hot s1/s2.
// ---------------------------------------------------------------------------
__global__ __launch_bounds__(256) void gat_gather(
    const int* __restrict__ cnt, const unsigned short* __restrict__ srcs,
    const float* __restrict__ s1, const float* __restrict__ s2,
    const unsigned short* __restrict__ z16,
    float* __restrict__ out)
{
    const int lane = threadIdx.x & 63;
    const int c    = lane & 15;
    const int q    = lane >> 4;
    const int n    = blockIdx.x * 4 + (threadIdx.x >> 6);
    if (n >= N_NODES) return;

    const int m = min(cnt[n], CAP);
    const float s2n = s2[n];                       // includes b_att
    const unsigned short* row = srcs + (size_t)n * CAP;

    float4 acc = make_float4(0.f, 0.f, 0.f, 0.f);
    int j = 0;
    for (; j + 4 <= m; j += 4) {
        const int src = row[j + q];
        float a = s1[src] + s2n;
        a = (a > 0.f) ? a : 0.01f * a;
        const ushort4 zz = *(const ushort4*)&z16[(size_t)src * OUT_DIM + 4 * c];
        acc.x += a * bf16_to_f32(zz.x);
        acc.y += a * bf16_to_f32(zz.y);
        acc.z += a * bf16_to_f32(zz.z);
        acc.w += a * bf16_to_f32(zz.w);
    }
    if (q < m - j) {
        const int src = row[j + q];
        float a = s1[src] + s2n;
        a = (a > 0.f) ? a : 0.01f * a;
        const ushort4 zz = *(const ushort4*)&z16[(size_t)src * OUT_DIM + 4 * c];
        acc.x += a * bf16_to_f32(zz.x);
        acc.y += a * bf16_to_f32(zz.y);
        acc.z += a * bf16_to_f32(zz.z);
        acc.w += a * bf16_to_f32(zz.w);
    }

    acc.x += __shfl_xor(acc.x, 16, 64);
    acc.y += __shfl_xor(acc.y, 16, 64);
    acc.z += __shfl_xor(acc.z, 16, 64);
    acc.w += __shfl_xor(acc.w, 16, 64);
    acc.x += __shfl_xor(acc.x, 32, 64);
    acc.y += __shfl_xor(acc.y, 32, 64);
    acc.z += __shfl_xor(acc.z, 32, 64);
    acc.w += __shfl_xor(acc.w, 32, 64);

    if (q == 0)
        *(float4*)&out[(size_t)n * OUT_DIM + 4 * c] = acc;
}

// ---------------------------------------------------------------------------
// K4: overflow cleanup (expected 0 iterations). Wave per overflow edge,
// fp atomics into out (runs after gather's plain stores — stream-ordered).
// ---------------------------------------------------------------------------
__global__ __launch_bounds__(64) void gat_overflow(
    const int* __restrict__ ovf, const int* __restrict__ cnt,
    const float* __restrict__ s1, const float* __restrict__ s2,
    const unsigned short* __restrict__ z16,
    float* __restrict__ out)
{
    const int lane = threadIdx.x & 63;
    const int novf = min(cnt[N_NODES], OVF_CAP);
    for (int e = blockIdx.x; e < novf; e += gridDim.x) {
        const int packed = ovf[e];
        const int dst = packed >> 16;
        const int src = packed & 0xFFFF;
        float a = s1[src] + s2[dst];
        a = (a > 0.f) ? a : 0.01f * a;
        unsafeAtomicAdd(&out[(size_t)dst * OUT_DIM + lane],
                        a * bf16_to_f32(z16[(size_t)src * OUT_DIM + lane]));
    }
}

extern "C" void kernel_launch(void* const* d_in, const int* in_sizes, int n_in,
                              void* d_out, int out_size, void* d_ws, size_t ws_size,
                              hipStream_t stream)
{
    const int*   adj  = (const int*)  d_in[0];   // (2, E)
    const float* h    = (const float*)d_in[1];   // (N, 128)
    const float* Wfc  = (const float*)d_in[2];   // (64, 128)
    const float* bfc  = (const float*)d_in[3];   // (64,)
    const float* Watt = (const float*)d_in[4];   // (1, 128)
    const float* batt = (const float*)d_in[5];   // (1,)
    float* out = (float*)d_out;                  // (N, 64)

    // ws layout (11.9 MB): z16[N*64] u16 | s1[N] f32 | s2[N] f32 |
    // cnt[N+1] i32 (last = ovf_cnt) | ovf[OVF_CAP] i32 | srcs[N*CAP] u16
    unsigned short* z16 = (unsigned short*)d_ws;
    float* s1  = (float*)(z16 + (size_t)N_NODES * OUT_DIM);
    float* s2  = s1 + N_NODES;
    int*   cnt = (int*)(s2 + N_NODES);
    int*   ovf = cnt + (N_NODES + 1);
    unsigned short* srcs = (unsigned short*)(ovf + OVF_CAP);

    const int nblk_edges = (E_EDGES + 255) / 256;   // 3125
    const int nblk_fc    = (MTILES + 3) / 4;        // 782

    hipMemsetAsync(cnt, 0, (N_NODES + 1) * sizeof(int), stream);

    gat_fc<<<nblk_fc, 256, 0, stream>>>(h, Wfc, bfc, Watt, batt, z16, s1, s2);
    gat_scatter<<<nblk_edges, 256, 0, stream>>>(adj, cnt, srcs, ovf);
    gat_gather<<<(N_NODES + 3) / 4, 256, 0, stream>>>(cnt, srcs, s1, s2, z16, out);
    gat_overflow<<<64, 64, 0, stream>>>(ovf, cnt, s1, s2, z16, out);
}

// Round 12
// 157.649 us; speedup vs baseline: 2.3088x; 1.1243x over previous
//
#include <hip/hip_runtime.h>
#include <hip/hip_bf16.h>

#define N_NODES 50000
#define E_EDGES 800000
#define IN_DIM  128
#define OUT_DIM 64
#define MTILES  (N_NODES / 16)   // 3125, exact
#define CAP     48               // per-node bin capacity (mean deg 16, Poisson)
#define OVF_CAP 32768            // overflow list capacity (expected use: 0)
#define NBLK_FC 782              // ceil(3125/4) fc blocks (4 tiles each)
#define NBLK_SC 2048             // 8 slices x 256 ranks
#define SLICE_N 6250             // 50000/8 dst nodes per slice
#define EPB     3125             // 800000/256 edges per scatter rank

static_assert(N_NODES % 16 == 0, "16-row MFMA tiles");
static_assert(N_NODES < 65536, "node ids packed as ushort");
static_assert(8 * SLICE_N == N_NODES, "slices partition dst space");
static_assert(256 * EPB == E_EDGES, "ranks partition edges");

// ws budget: round-1 proved >=13.2 MB OK; round-2's 16.8 MB corrupted memory.
// This layout: 11.9 MB.

typedef __attribute__((ext_vector_type(8))) short bf16x8;
typedef __attribute__((ext_vector_type(4))) float f32x4;

__device__ __forceinline__ unsigned short f32_to_bf16_rne(float f) {
    unsigned u = __float_as_uint(f);
    return (unsigned short)((u + 0x7FFFu + ((u >> 16) & 1u)) >> 16);
}
__device__ __forceinline__ float bf16_to_f32(unsigned short s) {
    return __uint_as_float(((unsigned)s) << 16);
}

// ---------------------------------------------------------------------------
// K1 (fused): blocks [0, NBLK_FC) run the MFMA fc (z16, s1, s2); blocks
// [NBLK_FC, NBLK_FC+NBLK_SC) run the XCD-sliced scatter. The two phases are
// independent until gather, so scatter's memory stalls overlap fc's MFMA.
//
// Scatter slicing (round-10 counters: scatter was bound by scattered
// partial-line write-through, WRITE 46.5 MB = 800k x 64B lines at 750 GB/s):
// group g = blockIdx%8 (block->XCD round-robin heuristic) handles only
// dst in [g*6250,(g+1)*6250). Its srcs slice (600 KB) + cnt slice (25 KB)
// stay in ONE XCD's L2 -> ~16 stores absorbed per line, evicted once.
// Correct under any block->XCD mapping; heuristic failure = neutral perf.
// ---------------------------------------------------------------------------
__global__ __launch_bounds__(256) void gat_fc_scatter(
    const float* __restrict__ h,
    const float* __restrict__ Wfc,
    const float* __restrict__ bfc,
    const float* __restrict__ Watt,
    const float* __restrict__ batt,
    const int*   __restrict__ adj,
    unsigned short* __restrict__ z16,
    float* __restrict__ s1,
    float* __restrict__ s2,
    int*   __restrict__ cnt,          // [N] pre-zeroed; cnt+N = ovf_cnt
    unsigned short* __restrict__ srcs,
    int*   __restrict__ ovf)
{
    __shared__ short Wlds[OUT_DIM][IN_DIM + 8];   // 17.4 KB (fc blocks only)

    if (blockIdx.x < NBLK_FC) {
        // ------------------------------ fc ------------------------------
        for (int i = threadIdx.x; i < OUT_DIM * IN_DIM; i += 256) {
            const int o = i >> 7;            // /128
            const int k = i & 127;
            Wlds[o][k] = (short)f32_to_bf16_rne(Wfc[i]);
        }
        __syncthreads();

        const int lane  = threadIdx.x & 63;
        const int c     = lane & 15;          // A row / B col / C col
        const int q     = lane >> 4;          // quad
        const int mtile = blockIdx.x * 4 + (threadIdx.x >> 6);
        if (mtile >= MTILES) return;
        const int n0 = mtile * 16;

        // B fragments: B[k=t*32+q*8+j][n=f*16+c] = W[f*16+c][t*32+q*8+j]
        bf16x8 B[4][4];
        #pragma unroll
        for (int t = 0; t < 4; ++t)
            #pragma unroll
            for (int f = 0; f < 4; ++f)
                B[t][f] = *(const bf16x8*)&Wlds[f * 16 + c][t * 32 + q * 8];

        f32x4 acc[4] = {{0,0,0,0},{0,0,0,0},{0,0,0,0},{0,0,0,0}};

        const float* arow = h + (size_t)(n0 + c) * IN_DIM + q * 8;
        #pragma unroll
        for (int t = 0; t < 4; ++t) {
            float4 x0 = *(const float4*)(arow + t * 32);
            float4 x1 = *(const float4*)(arow + t * 32 + 4);
            bf16x8 a;
            a[0] = (short)f32_to_bf16_rne(x0.x);
            a[1] = (short)f32_to_bf16_rne(x0.y);
            a[2] = (short)f32_to_bf16_rne(x0.z);
            a[3] = (short)f32_to_bf16_rne(x0.w);
            a[4] = (short)f32_to_bf16_rne(x1.x);
            a[5] = (short)f32_to_bf16_rne(x1.y);
            a[6] = (short)f32_to_bf16_rne(x1.z);
            a[7] = (short)f32_to_bf16_rne(x1.w);
            #pragma unroll
            for (int f = 0; f < 4; ++f)
                acc[f] = __builtin_amdgcn_mfma_f32_16x16x32_bf16(a, B[t][f], acc[f], 0, 0, 0);
        }

        const float batt0 = batt[0];
        float w1c[4], w2c[4], bv[4];
        #pragma unroll
        for (int f = 0; f < 4; ++f) {
            w1c[f] = Watt[f * 16 + c];
            w2c[f] = Watt[OUT_DIM + f * 16 + c];
            bv[f]  = bfc[f * 16 + c];
        }
        float p1[4] = {0,0,0,0}, p2[4] = {0,0,0,0};
        #pragma unroll
        for (int f = 0; f < 4; ++f)
            #pragma unroll
            for (int r = 0; r < 4; ++r) {
                const float v = acc[f][r] + bv[f];
                z16[(size_t)(n0 + q * 4 + r) * OUT_DIM + f * 16 + c] = f32_to_bf16_rne(v);
                p1[r] += v * w1c[f];
                p2[r] += v * w2c[f];
            }
        #pragma unroll
        for (int r = 0; r < 4; ++r) {
            #pragma unroll
            for (int off = 1; off < 16; off <<= 1) {
                p1[r] += __shfl_xor(p1[r], off, 64);
                p2[r] += __shfl_xor(p2[r], off, 64);
            }
            if (c == 0) {
                s1[n0 + q * 4 + r] = p1[r];
                s2[n0 + q * 4 + r] = p2[r] + batt0;   // fold b_att in
            }
        }
    } else {
        // ---------------------------- scatter ----------------------------
        const int k     = blockIdx.x - NBLK_FC;        // 0..2047
        const unsigned slice = blockIdx.x & 7;         // XCD heuristic
        const int rank  = k >> 3;                      // 0..255
        const unsigned lo = slice * SLICE_N;
        const int e0 = rank * EPB;
        const int e1 = e0 + EPB;

        for (int e = e0 + (int)threadIdx.x; e < e1; e += 256) {
            const unsigned dst = (unsigned)adj[E_EDGES + e];
            if (dst - lo < (unsigned)SLICE_N) {
                const int src = adj[e];
                const int pos = atomicAdd(&cnt[dst], 1);
                if (pos < CAP) {
                    srcs[(size_t)dst * CAP + pos] = (unsigned short)src;
                } else {
                    const int o = atomicAdd(&cnt[N_NODES], 1);   // ovf_cnt
                    if (o < OVF_CAP) ovf[o] = ((int)dst << 16) | src;
                }
            }
        }
    }
}

// ---------------------------------------------------------------------------
// K2: gather, quarter-wave layout (validated rounds 7/10). 16 lanes/edge,
// ushort4 z loads, 4 edges in flight. att recomputed from L2-hot s1/s2.
// ---------------------------------------------------------------------------
__global__ __launch_bounds__(256) void gat_gather(
    const int* __restrict__ cnt, const unsigned short* __restrict__ srcs,
    const float* __restrict__ s1, const float* __restrict__ s2,
    const unsigned short* __restrict__ z16,
    float* __restrict__ out)
{
    const int lane = threadIdx.x & 63;
    const int c    = lane & 15;
    const int q    = lane >> 4;
    const int n    = blockIdx.x * 4 + (threadIdx.x >> 6);
    if (n >= N_NODES) return;

    const int m = min(cnt[n], CAP);
    const float s2n = s2[n];                       // includes b_att
    const unsigned short* row = srcs + (size_t)n * CAP;

    float4 acc = make_float4(0.f, 0.f, 0.f, 0.f);
    int j = 0;
    for (; j + 4 <= m; j += 4) {
        const int src = row[j + q];
        float a = s1[src] + s2n;
        a = (a > 0.f) ? a : 0.01f * a;
        const ushort4 zz = *(const ushort4*)&z16[(size_t)src * OUT_DIM + 4 * c];
        acc.x += a * bf16_to_f32(zz.x);
        acc.y += a * bf16_to_f32(zz.y);
        acc.z += a * bf16_to_f32(zz.z);
        acc.w += a * bf16_to_f32(zz.w);
    }
    if (q < m - j) {
        const int src = row[j + q];
        float a = s1[src] + s2n;
        a = (a > 0.f) ? a : 0.01f * a;
        const ushort4 zz = *(const ushort4*)&z16[(size_t)src * OUT_DIM + 4 * c];
        acc.x += a * bf16_to_f32(zz.x);
        acc.y += a * bf16_to_f32(zz.y);
        acc.z += a * bf16_to_f32(zz.z);
        acc.w += a * bf16_to_f32(zz.w);
    }

    acc.x += __shfl_xor(acc.x, 16, 64);
    acc.y += __shfl_xor(acc.y, 16, 64);
    acc.z += __shfl_xor(acc.z, 16, 64);
    acc.w += __shfl_xor(acc.w, 16, 64);
    acc.x += __shfl_xor(acc.x, 32, 64);
    acc.y += __shfl_xor(acc.y, 32, 64);
    acc.z += __shfl_xor(acc.z, 32, 64);
    acc.w += __shfl_xor(acc.w, 32, 64);

    if (q == 0)
        *(float4*)&out[(size_t)n * OUT_DIM + 4 * c] = acc;
}

// ---------------------------------------------------------------------------
// K3: overflow cleanup (expected 0 iterations). Wave per overflow edge,
// fp atomics into out (runs after gather's plain stores — stream-ordered).
// ---------------------------------------------------------------------------
__global__ __launch_bounds__(64) void gat_overflow(
    const int* __restrict__ ovf, const int* __restrict__ cnt,
    const float* __restrict__ s1, const float* __restrict__ s2,
    const unsigned short* __restrict__ z16,
    float* __restrict__ out)
{
    const int lane = threadIdx.x & 63;
    const int novf = min(cnt[N_NODES], OVF_CAP);
    for (int e = blockIdx.x; e < novf; e += gridDim.x) {
        const int packed = ovf[e];
        const int dst = packed >> 16;
        const int src = packed & 0xFFFF;
        float a = s1[src] + s2[dst];
        a = (a > 0.f) ? a : 0.01f * a;
        unsafeAtomicAdd(&out[(size_t)dst * OUT_DIM + lane],
                        a * bf16_to_f32(z16[(size_t)src * OUT_DIM + lane]));
    }
}

extern "C" void kernel_launch(void* const* d_in, const int* in_sizes, int n_in,
                              void* d_out, int out_size, void* d_ws, size_t ws_size,
                              hipStream_t stream)
{
    const int*   adj  = (const int*)  d_in[0];   // (2, E)
    const float* h    = (const float*)d_in[1];   // (N, 128)
    const float* Wfc  = (const float*)d_in[2];   // (64, 128)
    const float* bfc  = (const float*)d_in[3];   // (64,)
    const float* Watt = (const float*)d_in[4];   // (1, 128)
    const float* batt = (const float*)d_in[5];   // (1,)
    float* out = (float*)d_out;                  // (N, 64)

    // ws layout (11.9 MB): z16[N*64] u16 | s1[N] f32 | s2[N] f32 |
    // cnt[N+1] i32 (last = ovf_cnt) | ovf[OVF_CAP] i32 | srcs[N*CAP] u16
    unsigned short* z16 = (unsigned short*)d_ws;
    float* s1  = (float*)(z16 + (size_t)N_NODES * OUT_DIM);
    float* s2  = s1 + N_NODES;
    int*   cnt = (int*)(s2 + N_NODES);
    int*   ovf = cnt + (N_NODES + 1);
    unsigned short* srcs = (unsigned short*)(ovf + OVF_CAP);

    hipMemsetAsync(cnt, 0, (N_NODES + 1) * sizeof(int), stream);

    gat_fc_scatter<<<NBLK_FC + NBLK_SC, 256, 0, stream>>>(
        h, Wfc, bfc, Watt, batt, adj, z16, s1, s2, cnt, srcs, ovf);
    gat_gather<<<(N_NODES + 3) / 4, 256, 0, stream>>>(cnt, srcs, s1, s2, z16, out);
    gat_overflow<<<64, 64, 0, stream>>>(ovf, cnt, s1, s2, z16, out);
}

// Round 13
// 151.326 us; speedup vs baseline: 2.4053x; 1.0418x over previous
//
#include <hip/hip_runtime.h>
#include <hip/hip_bf16.h>

#define N_NODES 50000
#define E_EDGES 800000
#define IN_DIM  128
#define OUT_DIM 64
#define MTILES  (N_NODES / 16)   // 3125, exact
#define CAP     40               // per-node bin capacity (mean deg 16, Poisson)
#define OVF_CAP 16384            // overflow list capacity (expected use: ~0)
#define CSTRIDE 8                // cnt stride in ints: 32B -> 2 counters/64B line
#define NBLK_FC 782              // ceil(3125/4) fc blocks (4 tiles each)
#define NBLK_SC 2048             // 8 slices x 256 ranks
#define SLICE_N 6250             // 50000/8 dst nodes per slice
#define EPB     3125             // 800000/256 edges per scatter rank

static_assert(N_NODES % 16 == 0, "16-row MFMA tiles");
static_assert(N_NODES < 65536, "node ids packed as ushort");
static_assert(8 * SLICE_N == N_NODES, "slices partition dst space");
static_assert(256 * EPB == E_EDGES, "ranks partition edges");

// ws budget: 13.2 MB proven OK (round 1); 16.8 MB corrupted memory (round 2).
// This layout: 6.4 (z16) + 0.4 (s1,s2) + 1.6 (padded cnt) + 0.065 (ovf)
//            + 4.0 (srcs) = 12.5 MB.

typedef __attribute__((ext_vector_type(8))) short bf16x8;
typedef __attribute__((ext_vector_type(4))) float f32x4;

__device__ __forceinline__ unsigned short f32_to_bf16_rne(float f) {
    unsigned u = __float_as_uint(f);
    return (unsigned short)((u + 0x7FFFu + ((u >> 16) & 1u)) >> 16);
}
__device__ __forceinline__ float bf16_to_f32(unsigned short s) {
    return __uint_as_float(((unsigned)s) << 16);
}

// ---------------------------------------------------------------------------
// K1 (fused): blocks [0, NBLK_FC) = MFMA fc; rest = XCD-sliced scatter.
//
// Round-12 diagnosis: 800k dst-atomics cost ~40-55 us in every structure
// (~15 G/s) with nothing classical saturated -> same-line serialization at
// the memory-side atomic point (cnt had 16 counters/line = 256 ops/line;
// WRITE 30 MB = 125 writebacks/line). Fix: cnt strided 32B -> 32 ops/line.
// ---------------------------------------------------------------------------
__global__ __launch_bounds__(256) void gat_fc_scatter(
    const float* __restrict__ h,
    const float* __restrict__ Wfc,
    const float* __restrict__ bfc,
    const float* __restrict__ Watt,
    const float* __restrict__ batt,
    const int*   __restrict__ adj,
    unsigned short* __restrict__ z16,
    float* __restrict__ s1,
    float* __restrict__ s2,
    int*   __restrict__ cntp,         // [N*CSTRIDE + CSTRIDE] pre-zeroed
    unsigned short* __restrict__ srcs,
    int*   __restrict__ ovf)
{
    __shared__ short Wlds[OUT_DIM][IN_DIM + 8];   // 17.4 KB (fc blocks only)

    if (blockIdx.x < NBLK_FC) {
        // ------------------------------ fc ------------------------------
        for (int i = threadIdx.x; i < OUT_DIM * IN_DIM; i += 256) {
            const int o = i >> 7;            // /128
            const int k = i & 127;
            Wlds[o][k] = (short)f32_to_bf16_rne(Wfc[i]);
        }
        __syncthreads();

        const int lane  = threadIdx.x & 63;
        const int c     = lane & 15;          // A row / B col / C col
        const int q     = lane >> 4;          // quad
        const int mtile = blockIdx.x * 4 + (threadIdx.x >> 6);
        if (mtile >= MTILES) return;
        const int n0 = mtile * 16;

        // B fragments: B[k=t*32+q*8+j][n=f*16+c] = W[f*16+c][t*32+q*8+j]
        bf16x8 B[4][4];
        #pragma unroll
        for (int t = 0; t < 4; ++t)
            #pragma unroll
            for (int f = 0; f < 4; ++f)
                B[t][f] = *(const bf16x8*)&Wlds[f * 16 + c][t * 32 + q * 8];

        f32x4 acc[4] = {{0,0,0,0},{0,0,0,0},{0,0,0,0},{0,0,0,0}};

        const float* arow = h + (size_t)(n0 + c) * IN_DIM + q * 8;
        #pragma unroll
        for (int t = 0; t < 4; ++t) {
            float4 x0 = *(const float4*)(arow + t * 32);
            float4 x1 = *(const float4*)(arow + t * 32 + 4);
            bf16x8 a;
            a[0] = (short)f32_to_bf16_rne(x0.x);
            a[1] = (short)f32_to_bf16_rne(x0.y);
            a[2] = (short)f32_to_bf16_rne(x0.z);
            a[3] = (short)f32_to_bf16_rne(x0.w);
            a[4] = (short)f32_to_bf16_rne(x1.x);
            a[5] = (short)f32_to_bf16_rne(x1.y);
            a[6] = (short)f32_to_bf16_rne(x1.z);
            a[7] = (short)f32_to_bf16_rne(x1.w);
            #pragma unroll
            for (int f = 0; f < 4; ++f)
                acc[f] = __builtin_amdgcn_mfma_f32_16x16x32_bf16(a, B[t][f], acc[f], 0, 0, 0);
        }

        const float batt0 = batt[0];
        float w1c[4], w2c[4], bv[4];
        #pragma unroll
        for (int f = 0; f < 4; ++f) {
            w1c[f] = Watt[f * 16 + c];
            w2c[f] = Watt[OUT_DIM + f * 16 + c];
            bv[f]  = bfc[f * 16 + c];
        }
        float p1[4] = {0,0,0,0}, p2[4] = {0,0,0,0};
        #pragma unroll
        for (int f = 0; f < 4; ++f)
            #pragma unroll
            for (int r = 0; r < 4; ++r) {
                const float v = acc[f][r] + bv[f];
                z16[(size_t)(n0 + q * 4 + r) * OUT_DIM + f * 16 + c] = f32_to_bf16_rne(v);
                p1[r] += v * w1c[f];
                p2[r] += v * w2c[f];
            }
        #pragma unroll
        for (int r = 0; r < 4; ++r) {
            #pragma unroll
            for (int off = 1; off < 16; off <<= 1) {
                p1[r] += __shfl_xor(p1[r], off, 64);
                p2[r] += __shfl_xor(p2[r], off, 64);
            }
            if (c == 0) {
                s1[n0 + q * 4 + r] = p1[r];
                s2[n0 + q * 4 + r] = p2[r] + batt0;   // fold b_att in
            }
        }
    } else {
        // ---------------------------- scatter ----------------------------
        const int k     = blockIdx.x - NBLK_FC;        // 0..2047
        const unsigned slice = blockIdx.x & 7;         // XCD heuristic
        const int rank  = k >> 3;                      // 0..255
        const unsigned lo = slice * SLICE_N;
        const int e0 = rank * EPB;
        const int e1 = e0 + EPB;

        for (int e = e0 + (int)threadIdx.x; e < e1; e += 256) {
            const unsigned dst = (unsigned)adj[E_EDGES + e];
            if (dst - lo < (unsigned)SLICE_N) {
                const int src = adj[e];
                const int pos = atomicAdd(&cntp[(size_t)dst * CSTRIDE], 1);
                if (pos < CAP) {
                    srcs[(size_t)dst * CAP + pos] = (unsigned short)src;
                } else {
                    const int o = atomicAdd(&cntp[(size_t)N_NODES * CSTRIDE], 1);
                    if (o < OVF_CAP) ovf[o] = ((int)dst << 16) | src;
                }
            }
        }
    }
}

// ---------------------------------------------------------------------------
// K2: gather, quarter-wave layout, MLP widened to 8 (round-12: gather is
// latency-bound at ~2 TB/s of L3-resident z traffic with only 4 chains).
// 16 lanes/edge, ushort4 z loads, 8 edges in flight per main iteration.
// ---------------------------------------------------------------------------
__global__ __launch_bounds__(256) void gat_gather(
    const int* __restrict__ cntp, const unsigned short* __restrict__ srcs,
    const float* __restrict__ s1, const float* __restrict__ s2,
    const unsigned short* __restrict__ z16,
    float* __restrict__ out)
{
    const int lane = threadIdx.x & 63;
    const int c    = lane & 15;
    const int q    = lane >> 4;
    const int n    = blockIdx.x * 4 + (threadIdx.x >> 6);
    if (n >= N_NODES) return;

    const int m = min(cntp[(size_t)n * CSTRIDE], CAP);
    const float s2n = s2[n];                       // includes b_att
    const unsigned short* row = srcs + (size_t)n * CAP;

    float4 acc = make_float4(0.f, 0.f, 0.f, 0.f);
    int j = 0;
    for (; j + 8 <= m; j += 8) {
        const int sA = row[j + q];
        const int sB = row[j + 4 + q];
        float aA = s1[sA] + s2n;
        float aB = s1[sB] + s2n;
        aA = (aA > 0.f) ? aA : 0.01f * aA;
        aB = (aB > 0.f) ? aB : 0.01f * aB;
        const ushort4 zA = *(const ushort4*)&z16[(size_t)sA * OUT_DIM + 4 * c];
        const ushort4 zB = *(const ushort4*)&z16[(size_t)sB * OUT_DIM + 4 * c];
        acc.x += aA * bf16_to_f32(zA.x) + aB * bf16_to_f32(zB.x);
        acc.y += aA * bf16_to_f32(zA.y) + aB * bf16_to_f32(zB.y);
        acc.z += aA * bf16_to_f32(zA.z) + aB * bf16_to_f32(zB.z);
        acc.w += aA * bf16_to_f32(zA.w) + aB * bf16_to_f32(zB.w);
    }
    if (j + 4 <= m) {
        const int src = row[j + q];
        float a = s1[src] + s2n;
        a = (a > 0.f) ? a : 0.01f * a;
        const ushort4 zz = *(const ushort4*)&z16[(size_t)src * OUT_DIM + 4 * c];
        acc.x += a * bf16_to_f32(zz.x);
        acc.y += a * bf16_to_f32(zz.y);
        acc.z += a * bf16_to_f32(zz.z);
        acc.w += a * bf16_to_f32(zz.w);
        j += 4;
    }
    if (q < m - j) {
        const int src = row[j + q];
        float a = s1[src] + s2n;
        a = (a > 0.f) ? a : 0.01f * a;
        const ushort4 zz = *(const ushort4*)&z16[(size_t)src * OUT_DIM + 4 * c];
        acc.x += a * bf16_to_f32(zz.x);
        acc.y += a * bf16_to_f32(zz.y);
        acc.z += a * bf16_to_f32(zz.z);
        acc.w += a * bf16_to_f32(zz.w);
    }

    acc.x += __shfl_xor(acc.x, 16, 64);
    acc.y += __shfl_xor(acc.y, 16, 64);
    acc.z += __shfl_xor(acc.z, 16, 64);
    acc.w += __shfl_xor(acc.w, 16, 64);
    acc.x += __shfl_xor(acc.x, 32, 64);
    acc.y += __shfl_xor(acc.y, 32, 64);
    acc.z += __shfl_xor(acc.z, 32, 64);
    acc.w += __shfl_xor(acc.w, 32, 64);

    if (q == 0)
        *(float4*)&out[(size_t)n * OUT_DIM + 4 * c] = acc;
}

// ---------------------------------------------------------------------------
// K3: overflow cleanup (expected ~0 iterations). Wave per overflow edge,
// fp atomics into out (stream-ordered after gather's plain stores).
// ---------------------------------------------------------------------------
__global__ __launch_bounds__(64) void gat_overflow(
    const int* __restrict__ ovf, const int* __restrict__ cntp,
    const float* __restrict__ s1, const float* __restrict__ s2,
    const unsigned short* __restrict__ z16,
    float* __restrict__ out)
{
    const int lane = threadIdx.x & 63;
    const int novf = min(cntp[(size_t)N_NODES * CSTRIDE], OVF_CAP);
    for (int e = blockIdx.x; e < novf; e += gridDim.x) {
        const int packed = ovf[e];
        const int dst = packed >> 16;
        const int src = packed & 0xFFFF;
        float a = s1[src] + s2[dst];
        a = (a > 0.f) ? a : 0.01f * a;
        unsafeAtomicAdd(&out[(size_t)dst * OUT_DIM + lane],
                        a * bf16_to_f32(z16[(size_t)src * OUT_DIM + lane]));
    }
}

extern "C" void kernel_launch(void* const* d_in, const int* in_sizes, int n_in,
                              void* d_out, int out_size, void* d_ws, size_t ws_size,
                              hipStream_t stream)
{
    const int*   adj  = (const int*)  d_in[0];   // (2, E)
    const float* h    = (const float*)d_in[1];   // (N, 128)
    const float* Wfc  = (const float*)d_in[2];   // (64, 128)
    const float* bfc  = (const float*)d_in[3];   // (64,)
    const float* Watt = (const float*)d_in[4];   // (1, 128)
    const float* batt = (const float*)d_in[5];   // (1,)
    float* out = (float*)d_out;                  // (N, 64)

    // ws layout (12.5 MB): z16[N*64] u16 | s1[N] f32 | s2[N] f32 |
    // cntp[N*8+8] i32 (32B-strided counters; [N*8] = ovf_cnt) |
    // ovf[OVF_CAP] i32 | srcs[N*CAP] u16
    unsigned short* z16 = (unsigned short*)d_ws;
    float* s1   = (float*)(z16 + (size_t)N_NODES * OUT_DIM);
    float* s2   = s1 + N_NODES;
    int*   cntp = (int*)(s2 + N_NODES);
    int*   ovf  = cntp + ((size_t)N_NODES * CSTRIDE + CSTRIDE);
    unsigned short* srcs = (unsigned short*)(ovf + OVF_CAP);

    hipMemsetAsync(cntp, 0, ((size_t)N_NODES * CSTRIDE + CSTRIDE) * sizeof(int),
                   stream);

    gat_fc_scatter<<<NBLK_FC + NBLK_SC, 256, 0, stream>>>(
        h, Wfc, bfc, Watt, batt, adj, z16, s1, s2, cntp, srcs, ovf);
    gat_gather<<<(N_NODES + 3) / 4, 256, 0, stream>>>(cntp, srcs, s1, s2, z16, out);
    gat_overflow<<<64, 64, 0, stream>>>(ovf, cntp, s1, s2, z16, out);
}

// Round 14
// 145.471 us; speedup vs baseline: 2.5021x; 1.0402x over previous
//
#include <hip/hip_runtime.h>
#include <hip/hip_bf16.h>

#define N_NODES 50000
#define E_EDGES 800000
#define IN_DIM  128
#define OUT_DIM 64
#define MTILES  (N_NODES / 16)   // 3125, exact
#define CAP     40               // per-node bin capacity (mean deg 16, Poisson)
#define OVF_CAP 16384            // overflow list capacity (expected use: ~0)
#define CSTRIDE 8                // cnt stride in ints: 32B -> 2 counters/64B line
#define NBLK_FC 782              // ceil(3125/4) fc blocks (4 tiles each)
#define NBLK_SC 2048             // 8 slices x 256 ranks
#define SLICE_N 6250             // 50000/8 dst nodes per slice
#define EPB     3125             // 800000/256 edges per scatter rank

static_assert(N_NODES % 16 == 0, "16-row MFMA tiles");
static_assert(N_NODES < 65536, "node ids packed as ushort");
static_assert(8 * SLICE_N == N_NODES, "slices partition dst space");
static_assert(256 * EPB == E_EDGES, "ranks partition edges");

// ws budget: 13.2 MB proven OK (round 1); 16.8 MB corrupted memory (round 2).
// This layout: 6.4 (z16) + 0.4 (s1,s2) + 1.6 (padded cnt) + 0.065 (ovf)
//            + 4.0 (srcs) = 12.5 MB.

typedef __attribute__((ext_vector_type(8))) short bf16x8;
typedef __attribute__((ext_vector_type(4))) float f32x4;
typedef __attribute__((ext_vector_type(8))) unsigned short u16x8;

__device__ __forceinline__ unsigned short f32_to_bf16_rne(float f) {
    unsigned u = __float_as_uint(f);
    return (unsigned short)((u + 0x7FFFu + ((u >> 16) & 1u)) >> 16);
}
__device__ __forceinline__ float bf16_to_f32(unsigned short s) {
    return __uint_as_float(((unsigned)s) << 16);
}

// ---------------------------------------------------------------------------
// K1 (fused): blocks [0, NBLK_FC) = MFMA fc; rest = XCD-sliced scatter.
// Scatter sits at the ~45 us memory-side returning-atomic floor (~17 G/s,
// rounds 7/10/12/13 — invariant to line spreading and XCD slicing), mostly
// hidden under fc. srcs plain stores DO benefit from XCD slicing (r12).
// ---------------------------------------------------------------------------
__global__ __launch_bounds__(256) void gat_fc_scatter(
    const float* __restrict__ h,
    const float* __restrict__ Wfc,
    const float* __restrict__ bfc,
    const float* __restrict__ Watt,
    const float* __restrict__ batt,
    const int*   __restrict__ adj,
    unsigned short* __restrict__ z16,
    float* __restrict__ s1,
    float* __restrict__ s2,
    int*   __restrict__ cntp,         // [N*CSTRIDE + CSTRIDE] pre-zeroed
    unsigned short* __restrict__ srcs,
    int*   __restrict__ ovf)
{
    __shared__ short Wlds[OUT_DIM][IN_DIM + 8];   // 17.4 KB (fc blocks only)

    if (blockIdx.x < NBLK_FC) {
        // ------------------------------ fc ------------------------------
        for (int i = threadIdx.x; i < OUT_DIM * IN_DIM; i += 256) {
            const int o = i >> 7;            // /128
            const int k = i & 127;
            Wlds[o][k] = (short)f32_to_bf16_rne(Wfc[i]);
        }
        __syncthreads();

        const int lane  = threadIdx.x & 63;
        const int c     = lane & 15;          // A row / B col / C col
        const int q     = lane >> 4;          // quad
        const int mtile = blockIdx.x * 4 + (threadIdx.x >> 6);
        if (mtile >= MTILES) return;
        const int n0 = mtile * 16;

        // B fragments: B[k=t*32+q*8+j][n=f*16+c] = W[f*16+c][t*32+q*8+j]
        bf16x8 B[4][4];
        #pragma unroll
        for (int t = 0; t < 4; ++t)
            #pragma unroll
            for (int f = 0; f < 4; ++f)
                B[t][f] = *(const bf16x8*)&Wlds[f * 16 + c][t * 32 + q * 8];

        f32x4 acc[4] = {{0,0,0,0},{0,0,0,0},{0,0,0,0},{0,0,0,0}};

        const float* arow = h + (size_t)(n0 + c) * IN_DIM + q * 8;
        #pragma unroll
        for (int t = 0; t < 4; ++t) {
            float4 x0 = *(const float4*)(arow + t * 32);
            float4 x1 = *(const float4*)(arow + t * 32 + 4);
            bf16x8 a;
            a[0] = (short)f32_to_bf16_rne(x0.x);
            a[1] = (short)f32_to_bf16_rne(x0.y);
            a[2] = (short)f32_to_bf16_rne(x0.z);
            a[3] = (short)f32_to_bf16_rne(x0.w);
            a[4] = (short)f32_to_bf16_rne(x1.x);
            a[5] = (short)f32_to_bf16_rne(x1.y);
            a[6] = (short)f32_to_bf16_rne(x1.z);
            a[7] = (short)f32_to_bf16_rne(x1.w);
            #pragma unroll
            for (int f = 0; f < 4; ++f)
                acc[f] = __builtin_amdgcn_mfma_f32_16x16x32_bf16(a, B[t][f], acc[f], 0, 0, 0);
        }

        const float batt0 = batt[0];
        float w1c[4], w2c[4], bv[4];
        #pragma unroll
        for (int f = 0; f < 4; ++f) {
            w1c[f] = Watt[f * 16 + c];
            w2c[f] = Watt[OUT_DIM + f * 16 + c];
            bv[f]  = bfc[f * 16 + c];
        }
        float p1[4] = {0,0,0,0}, p2[4] = {0,0,0,0};
        #pragma unroll
        for (int f = 0; f < 4; ++f)
            #pragma unroll
            for (int r = 0; r < 4; ++r) {
                const float v = acc[f][r] + bv[f];
                z16[(size_t)(n0 + q * 4 + r) * OUT_DIM + f * 16 + c] = f32_to_bf16_rne(v);
                p1[r] += v * w1c[f];
                p2[r] += v * w2c[f];
            }
        #pragma unroll
        for (int r = 0; r < 4; ++r) {
            #pragma unroll
            for (int off = 1; off < 16; off <<= 1) {
                p1[r] += __shfl_xor(p1[r], off, 64);
                p2[r] += __shfl_xor(p2[r], off, 64);
            }
            if (c == 0) {
                s1[n0 + q * 4 + r] = p1[r];
                s2[n0 + q * 4 + r] = p2[r] + batt0;   // fold b_att in
            }
        }
    } else {
        // ---------------------------- scatter ----------------------------
        const int k     = blockIdx.x - NBLK_FC;        // 0..2047
        const unsigned slice = blockIdx.x & 7;         // XCD heuristic
        const int rank  = k >> 3;                      // 0..255
        const unsigned lo = slice * SLICE_N;
        const int e0 = rank * EPB;
        const int e1 = e0 + EPB;

        for (int e = e0 + (int)threadIdx.x; e < e1; e += 256) {
            const unsigned dst = (unsigned)adj[E_EDGES + e];
            if (dst - lo < (unsigned)SLICE_N) {
                const int src = adj[e];
                const int pos = atomicAdd(&cntp[(size_t)dst * CSTRIDE], 1);
                if (pos < CAP) {
                    srcs[(size_t)dst * CAP + pos] = (unsigned short)src;
                } else {
                    const int o = atomicAdd(&cntp[(size_t)N_NODES * CSTRIDE], 1);
                    if (o < OVF_CAP) ovf[o] = ((int)dst << 16) | src;
                }
            }
        }
    }
}

// ---------------------------------------------------------------------------
// K2: gather. 8 lanes/edge (lane holds 8 features, ushort8 = 16B load — the
// coalescing sweet spot), 8 edge slots per wave -> 8 independent src->z
// chains, half the load instructions of the 16x4 layout. Overflow list is
// self-serviced per node (predicated scan; free when empty) — the separate
// overflow kernel and its fp atomics are gone. Out written exactly once.
// ---------------------------------------------------------------------------
__global__ __launch_bounds__(256) void gat_gather(
    const int* __restrict__ cntp, const unsigned short* __restrict__ srcs,
    const int* __restrict__ ovf,
    const float* __restrict__ s1, const float* __restrict__ s2,
    const unsigned short* __restrict__ z16,
    float* __restrict__ out)
{
    const int lane = threadIdx.x & 63;
    const int c    = lane & 7;        // feature group: features 8c..8c+7
    const int q    = lane >> 3;       // edge slot 0..7
    const int n    = blockIdx.x * 4 + (threadIdx.x >> 6);
    if (n >= N_NODES) return;

    const int m = min(cntp[(size_t)n * CSTRIDE], CAP);
    const float s2n = s2[n];                       // includes b_att
    const unsigned short* row = srcs + (size_t)n * CAP;

    float acc[8] = {0,0,0,0,0,0,0,0};
    int j = 0;
    for (; j + 8 <= m; j += 8) {
        const int src = row[j + q];
        float a = s1[src] + s2n;
        a = (a > 0.f) ? a : 0.01f * a;
        const u16x8 zz = *(const u16x8*)&z16[(size_t)src * OUT_DIM + 8 * c];
        #pragma unroll
        for (int t = 0; t < 8; ++t) acc[t] += a * bf16_to_f32(zz[t]);
    }
    if (q < m - j) {
        const int src = row[j + q];
        float a = s1[src] + s2n;
        a = (a > 0.f) ? a : 0.01f * a;
        const u16x8 zz = *(const u16x8*)&z16[(size_t)src * OUT_DIM + 8 * c];
        #pragma unroll
        for (int t = 0; t < 8; ++t) acc[t] += a * bf16_to_f32(zz[t]);
    }

    // self-service overflow (novf expected 0; one scalar load + skip)
    const int novf = min(cntp[(size_t)N_NODES * CSTRIDE], OVF_CAP);
    for (int base = 0; base < novf; base += 8) {
        const int idx = base + q;
        int packed = (idx < novf) ? ovf[idx] : -1;
        const bool valid = (idx < novf) && ((packed >> 16) == n);
        const int src = valid ? (packed & 0xFFFF) : 0;
        float a = s1[src] + s2n;
        a = (a > 0.f) ? a : 0.01f * a;
        a = valid ? a : 0.f;
        const u16x8 zz = *(const u16x8*)&z16[(size_t)src * OUT_DIM + 8 * c];
        #pragma unroll
        for (int t = 0; t < 8; ++t) acc[t] += a * bf16_to_f32(zz[t]);
    }

    // combine the 8 edge slots (slot index lives in lane bits 3..5)
    #pragma unroll
    for (int t = 0; t < 8; ++t) {
        acc[t] += __shfl_xor(acc[t], 8, 64);
        acc[t] += __shfl_xor(acc[t], 16, 64);
        acc[t] += __shfl_xor(acc[t], 32, 64);
    }

    if (q == 0) {
        float4 lo = make_float4(acc[0], acc[1], acc[2], acc[3]);
        float4 hi = make_float4(acc[4], acc[5], acc[6], acc[7]);
        *(float4*)&out[(size_t)n * OUT_DIM + 8 * c]     = lo;
        *(float4*)&out[(size_t)n * OUT_DIM + 8 * c + 4] = hi;
    }
}

extern "C" void kernel_launch(void* const* d_in, const int* in_sizes, int n_in,
                              void* d_out, int out_size, void* d_ws, size_t ws_size,
                              hipStream_t stream)
{
    const int*   adj  = (const int*)  d_in[0];   // (2, E)
    const float* h    = (const float*)d_in[1];   // (N, 128)
    const float* Wfc  = (const float*)d_in[2];   // (64, 128)
    const float* bfc  = (const float*)d_in[3];   // (64,)
    const float* Watt = (const float*)d_in[4];   // (1, 128)
    const float* batt = (const float*)d_in[5];   // (1,)
    float* out = (float*)d_out;                  // (N, 64)

    // ws layout (12.5 MB): z16[N*64] u16 | s1[N] f32 | s2[N] f32 |
    // cntp[N*8+8] i32 (32B-strided counters; [N*8] = ovf_cnt) |
    // ovf[OVF_CAP] i32 | srcs[N*CAP] u16
    unsigned short* z16 = (unsigned short*)d_ws;
    float* s1   = (float*)(z16 + (size_t)N_NODES * OUT_DIM);
    float* s2   = s1 + N_NODES;
    int*   cntp = (int*)(s2 + N_NODES);
    int*   ovf  = cntp + ((size_t)N_NODES * CSTRIDE + CSTRIDE);
    unsigned short* srcs = (unsigned short*)(ovf + OVF_CAP);

    hipMemsetAsync(cntp, 0, ((size_t)N_NODES * CSTRIDE + CSTRIDE) * sizeof(int),
                   stream);

    gat_fc_scatter<<<NBLK_FC + NBLK_SC, 256, 0, stream>>>(
        h, Wfc, bfc, Watt, batt, adj, z16, s1, s2, cntp, srcs, ovf);
    gat_gather<<<(N_NODES + 3) / 4, 256, 0, stream>>>(cntp, srcs, ovf,
                                                      s1, s2, z16, out);
}

// Round 15
// 134.947 us; speedup vs baseline: 2.6972x; 1.0780x over previous
//
#include <hip/hip_runtime.h>
#include <hip/hip_bf16.h>

#define N_NODES 50000
#define E_EDGES 800000
#define IN_DIM  128
#define OUT_DIM 64
#define MTILES  (N_NODES / 16)   // 3125, exact
#define NB      196              // coarse dst buckets (dst >> 8)
#define BCAP    6144             // bucket capacity: mean 4096, sd 64 -> +32 sigma
#define OVF_CAP 16384            // overflow list (expected use: 0)
#define NBLK_FC 782              // ceil(3125/4) fc blocks (4 tiles each)
#define NBLK_SA 256              // pass-A blocks
#define EPA     3125             // 800000/256 edges per pass-A block

static_assert(N_NODES % 16 == 0, "16-row MFMA tiles");
static_assert(N_NODES < 65536, "node ids packed in 16 bits");
static_assert(NBLK_SA * EPA == E_EDGES, "pass-A blocks partition edges");
static_assert(NB * 256 >= N_NODES, "buckets cover dst space");

// ws budget: 13.2 MB proven OK (round 1); 16.8 MB corrupted memory (round 2).
// This layout: 6.4 (z16) + 0.4 (s1,s2) + 0.4 (start,deg) + ~0.07 (gcnt,ovf)
//            + 4.8 (coarse) = 12.1 MB.

typedef __attribute__((ext_vector_type(8))) short bf16x8;
typedef __attribute__((ext_vector_type(4))) float f32x4;
typedef __attribute__((ext_vector_type(8))) unsigned short u16x8;

__device__ __forceinline__ unsigned short f32_to_bf16_rne(float f) {
    unsigned u = __float_as_uint(f);
    return (unsigned short)((u + 0x7FFFu + ((u >> 16) & 1u)) >> 16);
}
__device__ __forceinline__ float bf16_to_f32(unsigned short s) {
    return __uint_as_float(((unsigned)s) << 16);
}

// ---------------------------------------------------------------------------
// K1 (fused): blocks [0, NBLK_FC) = MFMA fc; blocks [NBLK_FC, +256) = pass A.
//
// Rounds 7-14 established: 800k global VALUE-RETURNING atomics cost ~40 us
// (~17-20 G/s) regardless of line spreading / XCD slicing, with ~29 MB of
// atomic write-through; fire-and-forget atomics ran 294 G/s (round 1).
// Pass A removes per-edge global returning atomics: LDS histogram over 196
// coarse buckets, ONE global returning atomic per bucket per block (50k
// total), LDS returning cursors for placement. Packed edge = dst<<16 | src.
// ---------------------------------------------------------------------------
__global__ __launch_bounds__(256) void gat_fc_scatter(
    const float* __restrict__ h,
    const float* __restrict__ Wfc,
    const float* __restrict__ bfc,
    const float* __restrict__ Watt,
    const float* __restrict__ batt,
    const int*   __restrict__ adj,
    unsigned short* __restrict__ z16,
    float* __restrict__ s1,
    float* __restrict__ s2,
    int*      __restrict__ gcnt,      // [NB+1] pre-zeroed; [NB] = ovf count
    unsigned* __restrict__ coarse,    // [NB*BCAP]
    unsigned* __restrict__ ovf)
{
    __shared__ short Wlds[OUT_DIM][IN_DIM + 8];   // 17.4 KB (fc blocks)
    __shared__ int bcnt[NB], gbase[NB], lcur[NB]; // 2.4 KB (pass-A blocks)

    if (blockIdx.x < NBLK_FC) {
        // ------------------------------ fc ------------------------------
        for (int i = threadIdx.x; i < OUT_DIM * IN_DIM; i += 256) {
            const int o = i >> 7;            // /128
            const int k = i & 127;
            Wlds[o][k] = (short)f32_to_bf16_rne(Wfc[i]);
        }
        __syncthreads();

        const int lane  = threadIdx.x & 63;
        const int c     = lane & 15;          // A row / B col / C col
        const int q     = lane >> 4;          // quad
        const int mtile = blockIdx.x * 4 + (threadIdx.x >> 6);
        if (mtile >= MTILES) return;
        const int n0 = mtile * 16;

        // B fragments: B[k=t*32+q*8+j][n=f*16+c] = W[f*16+c][t*32+q*8+j]
        bf16x8 B[4][4];
        #pragma unroll
        for (int t = 0; t < 4; ++t)
            #pragma unroll
            for (int f = 0; f < 4; ++f)
                B[t][f] = *(const bf16x8*)&Wlds[f * 16 + c][t * 32 + q * 8];

        f32x4 acc[4] = {{0,0,0,0},{0,0,0,0},{0,0,0,0},{0,0,0,0}};

        const float* arow = h + (size_t)(n0 + c) * IN_DIM + q * 8;
        #pragma unroll
        for (int t = 0; t < 4; ++t) {
            float4 x0 = *(const float4*)(arow + t * 32);
            float4 x1 = *(const float4*)(arow + t * 32 + 4);
            bf16x8 a;
            a[0] = (short)f32_to_bf16_rne(x0.x);
            a[1] = (short)f32_to_bf16_rne(x0.y);
            a[2] = (short)f32_to_bf16_rne(x0.z);
            a[3] = (short)f32_to_bf16_rne(x0.w);
            a[4] = (short)f32_to_bf16_rne(x1.x);
            a[5] = (short)f32_to_bf16_rne(x1.y);
            a[6] = (short)f32_to_bf16_rne(x1.z);
            a[7] = (short)f32_to_bf16_rne(x1.w);
            #pragma unroll
            for (int f = 0; f < 4; ++f)
                acc[f] = __builtin_amdgcn_mfma_f32_16x16x32_bf16(a, B[t][f], acc[f], 0, 0, 0);
        }

        const float batt0 = batt[0];
        float w1c[4], w2c[4], bv[4];
        #pragma unroll
        for (int f = 0; f < 4; ++f) {
            w1c[f] = Watt[f * 16 + c];
            w2c[f] = Watt[OUT_DIM + f * 16 + c];
            bv[f]  = bfc[f * 16 + c];
        }
        float p1[4] = {0,0,0,0}, p2[4] = {0,0,0,0};
        #pragma unroll
        for (int f = 0; f < 4; ++f)
            #pragma unroll
            for (int r = 0; r < 4; ++r) {
                const float v = acc[f][r] + bv[f];
                z16[(size_t)(n0 + q * 4 + r) * OUT_DIM + f * 16 + c] = f32_to_bf16_rne(v);
                p1[r] += v * w1c[f];
                p2[r] += v * w2c[f];
            }
        #pragma unroll
        for (int r = 0; r < 4; ++r) {
            #pragma unroll
            for (int off = 1; off < 16; off <<= 1) {
                p1[r] += __shfl_xor(p1[r], off, 64);
                p2[r] += __shfl_xor(p2[r], off, 64);
            }
            if (c == 0) {
                s1[n0 + q * 4 + r] = p1[r];
                s2[n0 + q * 4 + r] = p2[r] + batt0;   // fold b_att in
            }
        }
    } else {
        // --------------------------- pass A -----------------------------
        const int k  = blockIdx.x - NBLK_FC;          // 0..255
        const int e0 = k * EPA, e1 = e0 + EPA;

        for (int t = threadIdx.x; t < NB; t += 256) { bcnt[t] = 0; lcur[t] = 0; }
        __syncthreads();

        for (int e = e0 + (int)threadIdx.x; e < e1; e += 256)
            atomicAdd(&bcnt[adj[E_EDGES + e] >> 8], 1);
        __syncthreads();

        for (int t = threadIdx.x; t < NB; t += 256)
            gbase[t] = atomicAdd(&gcnt[t], bcnt[t]);   // 196 global atomics/block
        __syncthreads();

        for (int e = e0 + (int)threadIdx.x; e < e1; e += 256) {
            const unsigned dst = (unsigned)adj[E_EDGES + e];
            const unsigned src = (unsigned)adj[e];
            const int b = (int)(dst >> 8);
            const int p = atomicAdd(&lcur[b], 1) + gbase[b];   // LDS cursor
            const unsigned packed = (dst << 16) | src;
            if (p < BCAP) {
                coarse[(size_t)b * BCAP + p] = packed;
            } else {
                const int o = atomicAdd(&gcnt[NB], 1);
                if (o < OVF_CAP) ovf[o] = packed;
            }
        }
    }
}

// ---------------------------------------------------------------------------
// K2 (pass B): one block per bucket. Load bucket edges to LDS, LDS-histogram
// its 256 dsts, exclusive scan, emit start/deg per node, write edges back
// dst-sorted (all returning atomics in LDS).
// ---------------------------------------------------------------------------
__global__ __launch_bounds__(256) void gat_binsort(
    unsigned* __restrict__ coarse,
    const int* __restrict__ gcnt,
    int* __restrict__ start, int* __restrict__ deg)
{
    __shared__ unsigned el[BCAP];                 // 24.6 KB
    __shared__ int hist[256], sof[256], cur[256]; // 3 KB
    const int b  = blockIdx.x;
    const int t  = threadIdx.x;
    const int nb = min(gcnt[b], BCAP);

    for (int i = t; i < nb; i += 256) el[i] = coarse[(size_t)b * BCAP + i];
    hist[t] = 0;
    __syncthreads();

    for (int i = t; i < nb; i += 256)
        atomicAdd(&hist[(el[i] >> 16) & 255], 1);
    __syncthreads();

    const int v = hist[t];
    sof[t] = v;
    __syncthreads();
    #pragma unroll
    for (int o = 1; o < 256; o <<= 1) {
        const int add = (t >= o) ? sof[t - o] : 0;
        __syncthreads();
        sof[t] += add;
        __syncthreads();
    }
    const int excl = sof[t] - v;
    cur[t] = excl;
    const int n = b * 256 + t;
    if (n < N_NODES) {
        start[n] = b * BCAP + excl;
        deg[n]   = v;
    }
    __syncthreads();

    for (int i = t; i < nb; i += 256) {
        const unsigned e = el[i];
        const int p = atomicAdd(&cur[(e >> 16) & 255], 1);
        coarse[(size_t)b * BCAP + p] = e;
    }
}

// ---------------------------------------------------------------------------
// K3: gather (r14 8x8 structure). 8 lanes/edge (ushort8 = 16B z load),
// 8 edge slots -> 8 independent src->z chains. Reads dst-sorted packed
// edges via start/deg. Self-serviced overflow (expected empty). No atomics.
// ---------------------------------------------------------------------------
__global__ __launch_bounds__(256) void gat_gather(
    const int* __restrict__ start, const int* __restrict__ deg,
    const unsigned* __restrict__ coarse, const int* __restrict__ gcnt,
    const unsigned* __restrict__ ovf,
    const float* __restrict__ s1, const float* __restrict__ s2,
    const unsigned short* __restrict__ z16,
    float* __restrict__ out)
{
    const int lane = threadIdx.x & 63;
    const int c    = lane & 7;        // feature group: features 8c..8c+7
    const int q    = lane >> 3;       // edge slot 0..7
    const int n    = blockIdx.x * 4 + (threadIdx.x >> 6);
    if (n >= N_NODES) return;

    const int m  = deg[n];
    const int jb = start[n];
    const float s2n = s2[n];                       // includes b_att

    float acc[8] = {0,0,0,0,0,0,0,0};
    int j = 0;
    for (; j + 8 <= m; j += 8) {
        const int src = (int)(coarse[jb + j + q] & 0xFFFFu);
        float a = s1[src] + s2n;
        a = (a > 0.f) ? a : 0.01f * a;
        const u16x8 zz = *(const u16x8*)&z16[(size_t)src * OUT_DIM + 8 * c];
        #pragma unroll
        for (int t = 0; t < 8; ++t) acc[t] += a * bf16_to_f32(zz[t]);
    }
    if (q < m - j) {
        const int src = (int)(coarse[jb + j + q] & 0xFFFFu);
        float a = s1[src] + s2n;
        a = (a > 0.f) ? a : 0.01f * a;
        const u16x8 zz = *(const u16x8*)&z16[(size_t)src * OUT_DIM + 8 * c];
        #pragma unroll
        for (int t = 0; t < 8; ++t) acc[t] += a * bf16_to_f32(zz[t]);
    }

    // self-service overflow (expected 0; one scalar load + skip)
    const int novf = min(gcnt[NB], OVF_CAP);
    for (int base = 0; base < novf; base += 8) {
        const int idx = base + q;
        const unsigned packed = (idx < novf) ? ovf[idx] : 0xFFFFFFFFu;
        const bool valid = (idx < novf) && ((packed >> 16) == (unsigned)n);
        const int src = valid ? (int)(packed & 0xFFFFu) : 0;
        float a = s1[src] + s2n;
        a = (a > 0.f) ? a : 0.01f * a;
        a = valid ? a : 0.f;
        const u16x8 zz = *(const u16x8*)&z16[(size_t)src * OUT_DIM + 8 * c];
        #pragma unroll
        for (int t = 0; t < 8; ++t) acc[t] += a * bf16_to_f32(zz[t]);
    }

    // combine the 8 edge slots (slot index in lane bits 3..5)
    #pragma unroll
    for (int t = 0; t < 8; ++t) {
        acc[t] += __shfl_xor(acc[t], 8, 64);
        acc[t] += __shfl_xor(acc[t], 16, 64);
        acc[t] += __shfl_xor(acc[t], 32, 64);
    }

    if (q == 0) {
        float4 lo = make_float4(acc[0], acc[1], acc[2], acc[3]);
        float4 hi = make_float4(acc[4], acc[5], acc[6], acc[7]);
        *(float4*)&out[(size_t)n * OUT_DIM + 8 * c]     = lo;
        *(float4*)&out[(size_t)n * OUT_DIM + 8 * c + 4] = hi;
    }
}

extern "C" void kernel_launch(void* const* d_in, const int* in_sizes, int n_in,
                              void* d_out, int out_size, void* d_ws, size_t ws_size,
                              hipStream_t stream)
{
    const int*   adj  = (const int*)  d_in[0];   // (2, E)
    const float* h    = (const float*)d_in[1];   // (N, 128)
    const float* Wfc  = (const float*)d_in[2];   // (64, 128)
    const float* bfc  = (const float*)d_in[3];   // (64,)
    const float* Watt = (const float*)d_in[4];   // (1, 128)
    const float* batt = (const float*)d_in[5];   // (1,)
    float* out = (float*)d_out;                  // (N, 64)

    // ws layout (12.1 MB): z16[N*64] u16 | s1[N] | s2[N] | start[N] | deg[N]
    // | gcnt[NB+1] ([NB]=ovf count) | ovf[OVF_CAP] u32 | coarse[NB*BCAP] u32
    unsigned short* z16 = (unsigned short*)d_ws;
    float* s1    = (float*)(z16 + (size_t)N_NODES * OUT_DIM);
    float* s2    = s1 + N_NODES;
    int*   start = (int*)(s2 + N_NODES);
    int*   deg   = start + N_NODES;
    int*   gcnt  = deg + N_NODES;
    unsigned* ovf    = (unsigned*)(gcnt + NB + 1);
    unsigned* coarse = ovf + OVF_CAP;

    hipMemsetAsync(gcnt, 0, (NB + 1) * sizeof(int), stream);

    gat_fc_scatter<<<NBLK_FC + NBLK_SA, 256, 0, stream>>>(
        h, Wfc, bfc, Watt, batt, adj, z16, s1, s2, gcnt, coarse, ovf);
    gat_binsort<<<NB, 256, 0, stream>>>(coarse, gcnt, start, deg);
    gat_gather<<<(N_NODES + 3) / 4, 256, 0, stream>>>(
        start, deg, coarse, gcnt, ovf, s1, s2, z16, out);
}

// Round 16
// 134.851 us; speedup vs baseline: 2.6991x; 1.0007x over previous
//
#include <hip/hip_runtime.h>
#include <hip/hip_bf16.h>

#define N_NODES 50000
#define E_EDGES 800000
#define IN_DIM  128
#define OUT_DIM 64
#define MTILES  (N_NODES / 16)   // 3125, exact
#define NB      196              // coarse dst buckets (dst >> 8)
#define BCAP    6144             // bucket capacity: mean 4096, sd 64 -> +32 sigma
#define OVF_CAP 16384            // overflow list (expected use: 0)
#define NBLK_FC 782              // ceil(3125/4) fc blocks (4 tiles each)
#define NBLK_SA 256              // pass-A blocks
#define EPA     3125             // 800000/256 edges per pass-A block

static_assert(N_NODES % 16 == 0, "16-row MFMA tiles");
static_assert(N_NODES < 65536, "node ids packed in 16 bits");
static_assert(NBLK_SA * EPA == E_EDGES, "pass-A blocks partition edges");
static_assert(NB * 256 >= N_NODES, "buckets cover dst space");

// ws: harness provides 256 MB (round-15 fillBuffer evidence); this layout
// uses 12.1 MB. (Round-2's "corruption at 16.8 MB" conclusion now suspect,
// but no need to expand.)

typedef __attribute__((ext_vector_type(8))) short bf16x8;
typedef __attribute__((ext_vector_type(4))) float f32x4;
typedef __attribute__((ext_vector_type(8))) unsigned short u16x8;

__device__ __forceinline__ unsigned short f32_to_bf16_rne(float f) {
    unsigned u = __float_as_uint(f);
    return (unsigned short)((u + 0x7FFFu + ((u >> 16) & 1u)) >> 16);
}
__device__ __forceinline__ float bf16_to_f32(unsigned short s) {
    return __uint_as_float(((unsigned)s) << 16);
}

// ---------------------------------------------------------------------------
// K1 (fused): blocks [0, NBLK_FC) = MFMA fc; blocks [NBLK_FC, +256) = pass A.
//
// Pass A (round-16 version): whole block's 3125 edges are histogrammed,
// bucket-SORTED IN LDS, then copied out so that consecutive entries within
// a bucket hit consecutive global addresses (~64-B segments; ~4 lines/wave
// instead of 64). Per-edge returning atomics live entirely in LDS; global
// returning atomics: 196/block (gbase allocation) = 50k total.
// ---------------------------------------------------------------------------
__global__ __launch_bounds__(256) void gat_fc_scatter(
    const float* __restrict__ h,
    const float* __restrict__ Wfc,
    const float* __restrict__ bfc,
    const float* __restrict__ Watt,
    const float* __restrict__ batt,
    const int*   __restrict__ adj,
    unsigned short* __restrict__ z16,
    float* __restrict__ s1,
    float* __restrict__ s2,
    int*      __restrict__ gcnt,      // [NB+1] pre-zeroed; [NB] = ovf count
    unsigned* __restrict__ coarse,    // [NB*BCAP]
    unsigned* __restrict__ ovf)
{
    __shared__ short Wlds[OUT_DIM][IN_DIM + 8];   // 17.4 KB (fc blocks)

    if (blockIdx.x < NBLK_FC) {
        // ------------------------------ fc ------------------------------
        for (int i = threadIdx.x; i < OUT_DIM * IN_DIM; i += 256) {
            const int o = i >> 7;            // /128
            const int k = i & 127;
            Wlds[o][k] = (short)f32_to_bf16_rne(Wfc[i]);
        }
        __syncthreads();

        const int lane  = threadIdx.x & 63;
        const int c     = lane & 15;          // A row / B col / C col
        const int q     = lane >> 4;          // quad
        const int mtile = blockIdx.x * 4 + (threadIdx.x >> 6);
        if (mtile >= MTILES) return;
        const int n0 = mtile * 16;

        // B fragments: B[k=t*32+q*8+j][n=f*16+c] = W[f*16+c][t*32+q*8+j]
        bf16x8 B[4][4];
        #pragma unroll
        for (int t = 0; t < 4; ++t)
            #pragma unroll
            for (int f = 0; f < 4; ++f)
                B[t][f] = *(const bf16x8*)&Wlds[f * 16 + c][t * 32 + q * 8];

        f32x4 acc[4] = {{0,0,0,0},{0,0,0,0},{0,0,0,0},{0,0,0,0}};

        const float* arow = h + (size_t)(n0 + c) * IN_DIM + q * 8;
        #pragma unroll
        for (int t = 0; t < 4; ++t) {
            float4 x0 = *(const float4*)(arow + t * 32);
            float4 x1 = *(const float4*)(arow + t * 32 + 4);
            bf16x8 a;
            a[0] = (short)f32_to_bf16_rne(x0.x);
            a[1] = (short)f32_to_bf16_rne(x0.y);
            a[2] = (short)f32_to_bf16_rne(x0.z);
            a[3] = (short)f32_to_bf16_rne(x0.w);
            a[4] = (short)f32_to_bf16_rne(x1.x);
            a[5] = (short)f32_to_bf16_rne(x1.y);
            a[6] = (short)f32_to_bf16_rne(x1.z);
            a[7] = (short)f32_to_bf16_rne(x1.w);
            #pragma unroll
            for (int f = 0; f < 4; ++f)
                acc[f] = __builtin_amdgcn_mfma_f32_16x16x32_bf16(a, B[t][f], acc[f], 0, 0, 0);
        }

        const float batt0 = batt[0];
        float w1c[4], w2c[4], bv[4];
        #pragma unroll
        for (int f = 0; f < 4; ++f) {
            w1c[f] = Watt[f * 16 + c];
            w2c[f] = Watt[OUT_DIM + f * 16 + c];
            bv[f]  = bfc[f * 16 + c];
        }
        float p1[4] = {0,0,0,0}, p2[4] = {0,0,0,0};
        #pragma unroll
        for (int f = 0; f < 4; ++f)
            #pragma unroll
            for (int r = 0; r < 4; ++r) {
                const float v = acc[f][r] + bv[f];
                z16[(size_t)(n0 + q * 4 + r) * OUT_DIM + f * 16 + c] = f32_to_bf16_rne(v);
                p1[r] += v * w1c[f];
                p2[r] += v * w2c[f];
            }
        #pragma unroll
        for (int r = 0; r < 4; ++r) {
            #pragma unroll
            for (int off = 1; off < 16; off <<= 1) {
                p1[r] += __shfl_xor(p1[r], off, 64);
                p2[r] += __shfl_xor(p2[r], off, 64);
            }
            if (c == 0) {
                s1[n0 + q * 4 + r] = p1[r];
                s2[n0 + q * 4 + r] = p2[r] + batt0;   // fold b_att in
            }
        }
    } else {
        // --------------------------- pass A -----------------------------
        __shared__ unsigned el[EPA];                  // 12.5 KB, bucket-sorted
        __shared__ int sof[256];                      // scan workspace
        __shared__ int bexc[NB], lcur[NB], gbase[NB]; // 2.4 KB

        const int k  = blockIdx.x - NBLK_FC;          // 0..255
        const int e0 = k * EPA;
        const int t  = threadIdx.x;

        sof[t] = 0;
        __syncthreads();

        // 1) LDS histogram of this block's 3125 dsts
        for (int i = t; i < EPA; i += 256)
            atomicAdd(&sof[adj[E_EDGES + e0 + i] >> 8], 1);
        __syncthreads();
        const int v = sof[t];
        __syncthreads();

        // 2) exclusive scan (Hillis-Steele, 256-wide; entries >= NB are 0)
        sof[t] = v;
        __syncthreads();
        #pragma unroll
        for (int o = 1; o < 256; o <<= 1) {
            const int add = (t >= o) ? sof[t - o] : 0;
            __syncthreads();
            sof[t] += add;
            __syncthreads();
        }
        if (t < NB) {
            const int excl = sof[t] - v;
            bexc[t]  = excl;
            lcur[t]  = excl;
            gbase[t] = atomicAdd(&gcnt[t], v);   // 196 global atomics/block
        }
        __syncthreads();

        // 3) place edges bucket-sorted into LDS (LDS returning cursors)
        for (int i = t; i < EPA; i += 256) {
            const unsigned dst = (unsigned)adj[E_EDGES + e0 + i];
            const unsigned src = (unsigned)adj[e0 + i];
            const int b = (int)(dst >> 8);
            const int p = atomicAdd(&lcur[b], 1);
            el[p] = (dst << 16) | src;
        }
        __syncthreads();

        // 4) coalesced copy-out: consecutive i within a bucket -> consecutive
        //    global addresses (segments of ~16 u32 = 64 B)
        for (int i = t; i < EPA; i += 256) {
            const unsigned packed = el[i];
            const int b = (int)(packed >> 24);           // dst>>8
            const int pin = gbase[b] + (i - bexc[b]);
            if (pin < BCAP) {
                coarse[(size_t)b * BCAP + pin] = packed;
            } else {
                const int o = atomicAdd(&gcnt[NB], 1);
                if (o < OVF_CAP) ovf[o] = packed;
            }
        }
    }
}

// ---------------------------------------------------------------------------
// K2 (pass B): one block per bucket. Load bucket edges to LDS, LDS-histogram
// its 256 dsts, exclusive scan, emit start/deg per node, write edges back
// dst-sorted (all returning atomics in LDS).
// ---------------------------------------------------------------------------
__global__ __launch_bounds__(256) void gat_binsort(
    unsigned* __restrict__ coarse,
    const int* __restrict__ gcnt,
    int* __restrict__ start, int* __restrict__ deg)
{
    __shared__ unsigned el[BCAP];                 // 24.6 KB
    __shared__ int hist[256], sof[256], cur[256]; // 3 KB
    const int b  = blockIdx.x;
    const int t  = threadIdx.x;
    const int nb = min(gcnt[b], BCAP);

    for (int i = t; i < nb; i += 256) el[i] = coarse[(size_t)b * BCAP + i];
    hist[t] = 0;
    __syncthreads();

    for (int i = t; i < nb; i += 256)
        atomicAdd(&hist[(el[i] >> 16) & 255], 1);
    __syncthreads();

    const int v = hist[t];
    sof[t] = v;
    __syncthreads();
    #pragma unroll
    for (int o = 1; o < 256; o <<= 1) {
        const int add = (t >= o) ? sof[t - o] : 0;
        __syncthreads();
        sof[t] += add;
        __syncthreads();
    }
    const int excl = sof[t] - v;
    cur[t] = excl;
    const int n = b * 256 + t;
    if (n < N_NODES) {
        start[n] = b * BCAP + excl;
        deg[n]   = v;
    }
    __syncthreads();

    for (int i = t; i < nb; i += 256) {
        const unsigned e = el[i];
        const int p = atomicAdd(&cur[(e >> 16) & 255], 1);
        coarse[(size_t)b * BCAP + p] = e;
    }
}

// ---------------------------------------------------------------------------
// K3: gather (validated r14/r15 8x8 structure). 8 lanes/edge (ushort8 = 16B
// z load), 8 edge slots -> 8 independent src->z chains. Reads dst-sorted
// packed edges via start/deg. Self-serviced overflow. No atomics.
// ---------------------------------------------------------------------------
__global__ __launch_bounds__(256) void gat_gather(
    const int* __restrict__ start, const int* __restrict__ deg,
    const unsigned* __restrict__ coarse, const int* __restrict__ gcnt,
    const unsigned* __restrict__ ovf,
    const float* __restrict__ s1, const float* __restrict__ s2,
    const unsigned short* __restrict__ z16,
    float* __restrict__ out)
{
    const int lane = threadIdx.x & 63;
    const int c    = lane & 7;        // feature group: features 8c..8c+7
    const int q    = lane >> 3;       // edge slot 0..7
    const int n    = blockIdx.x * 4 + (threadIdx.x >> 6);
    if (n >= N_NODES) return;

    const int m  = deg[n];
    const int jb = start[n];
    const float s2n = s2[n];                       // includes b_att

    float acc[8] = {0,0,0,0,0,0,0,0};
    int j = 0;
    for (; j + 8 <= m; j += 8) {
        const int src = (int)(coarse[jb + j + q] & 0xFFFFu);
        float a = s1[src] + s2n;
        a = (a > 0.f) ? a : 0.01f * a;
        const u16x8 zz = *(const u16x8*)&z16[(size_t)src * OUT_DIM + 8 * c];
        #pragma unroll
        for (int t = 0; t < 8; ++t) acc[t] += a * bf16_to_f32(zz[t]);
    }
    if (q < m - j) {
        const int src = (int)(coarse[jb + j + q] & 0xFFFFu);
        float a = s1[src] + s2n;
        a = (a > 0.f) ? a : 0.01f * a;
        const u16x8 zz = *(const u16x8*)&z16[(size_t)src * OUT_DIM + 8 * c];
        #pragma unroll
        for (int t = 0; t < 8; ++t) acc[t] += a * bf16_to_f32(zz[t]);
    }

    // self-service overflow (expected 0; one scalar load + skip)
    const int novf = min(gcnt[NB], OVF_CAP);
    for (int base = 0; base < novf; base += 8) {
        const int idx = base + q;
        const unsigned packed = (idx < novf) ? ovf[idx] : 0xFFFFFFFFu;
        const bool valid = (idx < novf) && ((packed >> 16) == (unsigned)n);
        const int src = valid ? (int)(packed & 0xFFFFu) : 0;
        float a = s1[src] + s2n;
        a = (a > 0.f) ? a : 0.01f * a;
        a = valid ? a : 0.f;
        const u16x8 zz = *(const u16x8*)&z16[(size_t)src * OUT_DIM + 8 * c];
        #pragma unroll
        for (int t = 0; t < 8; ++t) acc[t] += a * bf16_to_f32(zz[t]);
    }

    // combine the 8 edge slots (slot index in lane bits 3..5)
    #pragma unroll
    for (int t = 0; t < 8; ++t) {
        acc[t] += __shfl_xor(acc[t], 8, 64);
        acc[t] += __shfl_xor(acc[t], 16, 64);
        acc[t] += __shfl_xor(acc[t], 32, 64);
    }

    if (q == 0) {
        float4 lo = make_float4(acc[0], acc[1], acc[2], acc[3]);
        float4 hi = make_float4(acc[4], acc[5], acc[6], acc[7]);
        *(float4*)&out[(size_t)n * OUT_DIM + 8 * c]     = lo;
        *(float4*)&out[(size_t)n * OUT_DIM + 8 * c + 4] = hi;
    }
}

extern "C" void kernel_launch(void* const* d_in, const int* in_sizes, int n_in,
                              void* d_out, int out_size, void* d_ws, size_t ws_size,
                              hipStream_t stream)
{
    const int*   adj  = (const int*)  d_in[0];   // (2, E)
    const float* h    = (const float*)d_in[1];   // (N, 128)
    const float* Wfc  = (const float*)d_in[2];   // (64, 128)
    const float* bfc  = (const float*)d_in[3];   // (64,)
    const float* Watt = (const float*)d_in[4];   // (1, 128)
    const float* batt = (const float*)d_in[5];   // (1,)
    float* out = (float*)d_out;                  // (N, 64)

    // ws layout (12.1 MB): z16[N*64] u16 | s1[N] | s2[N] | start[N] | deg[N]
    // | gcnt[NB+1] ([NB]=ovf count) | ovf[OVF_CAP] u32 | coarse[NB*BCAP] u32
    unsigned short* z16 = (unsigned short*)d_ws;
    float* s1    = (float*)(z16 + (size_t)N_NODES * OUT_DIM);
    float* s2    = s1 + N_NODES;
    int*   start = (int*)(s2 + N_NODES);
    int*   deg   = start + N_NODES;
    int*   gcnt  = deg + N_NODES;
    unsigned* ovf    = (unsigned*)(gcnt + NB + 1);
    unsigned* coarse = ovf + OVF_CAP;

    hipMemsetAsync(gcnt, 0, (NB + 1) * sizeof(int), stream);

    gat_fc_scatter<<<NBLK_FC + NBLK_SA, 256, 0, stream>>>(
        h, Wfc, bfc, Watt, batt, adj, z16, s1, s2, gcnt, coarse, ovf);
    gat_binsort<<<NB, 256, 0, stream>>>(coarse, gcnt, start, deg);
    gat_gather<<<(N_NODES + 3) / 4, 256, 0, stream>>>(
        start, deg, coarse, gcnt, ovf, s1, s2, z16, out);
}